// Round 7
// baseline (274.348 us; speedup 1.0000x reference)
//
#include <hip/hip_runtime.h>
#include <hip/hip_bf16.h>

#define F 128
#define NG 512

typedef __attribute__((ext_vector_type(8))) short s16x8;
typedef __attribute__((ext_vector_type(4))) float f32x4;

__device__ inline float bf2f(unsigned short u) {
    unsigned int x = ((unsigned int)u) << 16;
    return __builtin_bit_cast(float, x);
}
__device__ inline unsigned short f2bf(float f) {
    __hip_bfloat16 h = __float2bfloat16(f);
    return __builtin_bit_cast(unsigned short, h);
}
__device__ inline unsigned int pack16(float x, float y) {
    return (unsigned int)f2bf(x) | ((unsigned int)f2bf(y) << 16);
}

// ---------------- prep: cast X (f32->bf16 row+col major) and shuffle weights ----------------

__global__ __launch_bounds__(256) void prep_kernel(const float* __restrict__ X,
                                                   unsigned short* __restrict__ Xr,
                                                   unsigned short* __restrict__ Xc,
                                                   const float* __restrict__ W1,
                                                   const float* __restrict__ W2,
                                                   unsigned short* __restrict__ o1,
                                                   unsigned short* __restrict__ o2) {
    __shared__ unsigned short tile[64][F + 4];
    int tid = threadIdx.x;
    if (blockIdx.x < 512) {
        int g = blockIdx.x >> 3;
        int nt = blockIdx.x & 7;
        int node0 = nt * 64;
        const float* Xg = X + ((size_t)g * NG + node0) * F;
        unsigned short* Xrg = Xr + ((size_t)g * NG + node0) * F;
        #pragma unroll
        for (int u = tid; u < 64 * 32; u += 256) {
            int row = u >> 5, c4 = u & 31;
            float4 v = ((const float4*)(Xg + (size_t)row * F))[c4];
            unsigned short a0 = f2bf(v.x), a1 = f2bf(v.y), a2 = f2bf(v.z), a3 = f2bf(v.w);
            tile[row][c4 * 4 + 0] = a0;
            tile[row][c4 * 4 + 1] = a1;
            tile[row][c4 * 4 + 2] = a2;
            tile[row][c4 * 4 + 3] = a3;
            uint2 w;
            w.x = (unsigned int)a0 | ((unsigned int)a1 << 16);
            w.y = (unsigned int)a2 | ((unsigned int)a3 << 16);
            ((uint2*)(Xrg + (size_t)row * F))[c4] = w;
        }
        __syncthreads();
        unsigned short* Xcg = Xc + (size_t)g * F * NG;
        #pragma unroll
        for (int u = tid; u < F * 16; u += 256) {
            int f = u >> 4, nb = u & 15;
            int n0 = nb * 4;
            uint2 w;
            w.x = (unsigned int)tile[n0 + 0][f] | ((unsigned int)tile[n0 + 1][f] << 16);
            w.y = (unsigned int)tile[n0 + 2][f] | ((unsigned int)tile[n0 + 3][f] << 16);
            ((uint2*)(Xcg + (size_t)f * NG + node0))[nb] = w;
        }
    } else {
        int t = (blockIdx.x - 512) * 256 + tid;   // [0, 98304)
        const float* W = (t < 49152) ? W1 : W2;
        unsigned short* o = (t < 49152) ? o1 : o2;
        int tt = (t < 49152) ? t : t - 49152;
        int j = tt & 7;
        int lane = (tt >> 3) & 63;
        int ct = (tt >> 9) & 7;
        int ks = tt >> 12;
        int k = ks * 32 + (lane >> 4) * 8 + j;
        int c = ct * 16 + (lane & 15);
        o[tt] = f2bf(W[(size_t)k * F + c]);
    }
}

// ---------------- dense S build ----------------

__global__ void cnt_scatter_kernel(const int* __restrict__ src, const int* __restrict__ dst,
                                   unsigned int* __restrict__ cnt32, int E) {
    int e = blockIdx.x * blockDim.x + threadIdx.x;
    if (e >= E) return;
    int s = src[e], d = dst[e];
    size_t idx = ((size_t)s << 9) | (unsigned)(d & (NG - 1));
    atomicAdd(&cnt32[idx >> 2], 1u << ((idx & 3) * 8));
}

__global__ __launch_bounds__(256) void sgen_kernel(const unsigned char* __restrict__ cnt,
                                                   unsigned short* __restrict__ Sb,
                                                   const float* __restrict__ alphap) {
    size_t t = (size_t)blockIdx.x * 256 + threadIdx.x;
    size_t base = t * 8;
    float alpha = *alphap;
    float diag = 1.0f - alpha;
    int i = (int)((base >> 9) & (NG - 1));
    int j0 = (int)(base & (NG - 1));
    uint2 c = *(const uint2*)(cnt + base);
    unsigned short o[8];
    #pragma unroll
    for (int b = 0; b < 8; ++b) {
        unsigned cv = ((b < 4) ? (c.x >> (8 * b)) : (c.y >> (8 * (b - 4)))) & 0xffu;
        float v = alpha * (float)cv + ((i == j0 + b) ? diag : 0.f);
        o[b] = f2bf(v);
    }
    uint4 w;
    w.x = (unsigned int)o[0] | ((unsigned int)o[1] << 16);
    w.y = (unsigned int)o[2] | ((unsigned int)o[3] << 16);
    w.z = (unsigned int)o[4] | ((unsigned int)o[5] << 16);
    w.w = (unsigned int)o[6] | ((unsigned int)o[7] << 16);
    *(uint4*)(Sb + base) = w;
}

// ---------------- merged layer kernel ----------------
// phase A: stage Bc -> Bs; t1 quarter = S@B -> Tt (LDS, XOR swz) + Tc (global col-major)
// grid barrier (software; grid=256 co-resident at 160KB LDS)
// phase B: stage Tc -> Bs; t2 quarter = S@t1 -> Bs tile [128][136];
//          h = A0r@W0 + t1(Tt)@W1 + t2@W2 + b; relu
// WRITE_H=1: h -> Hr (row) + Hc (col).  WRITE_H=0: per-block col max -> pooledp[rt][g][F].

template <int WRITE_H>
__global__ __launch_bounds__(512) void layer_kernel(
    const unsigned short* __restrict__ S, const unsigned short* __restrict__ Bc,
    const unsigned short* __restrict__ A0r, unsigned short* __restrict__ Tc,
    const unsigned short* __restrict__ Wswz, const float* __restrict__ bias,
    unsigned short* __restrict__ Hr, unsigned short* __restrict__ Hc,
    float* __restrict__ pooledp, unsigned int* __restrict__ barctr) {
    __shared__ unsigned short Bs[65536];   // 128 KB
    __shared__ unsigned short Tt[16384];   // 32 KB : t1 tile, XOR-swizzled [128][128]
    // XCD-chunked swizzle: all 4 blocks of a graph land on one XCD
    const int id = (blockIdx.x & 7) * 32 + (blockIdx.x >> 3);
    const int g = id >> 2, rt = id & 3;
    const int tid = threadIdx.x, wave = tid >> 6, lane = tid & 63;
    const int l15 = lane & 15, hi = lane >> 4;
    const int lrow = wave * 16 + l15;
    const int rloc = wave * 16 + (hi << 2);
    const int bxor = l15 & 7;
    const unsigned short* Sg = S + ((size_t)g * NG + rt * 128 + lrow) * NG;

    // ---- phase A ----
    {
        const unsigned short* Bcg = Bc + (size_t)g * F * NG;
        #pragma unroll
        for (int it = 0; it < 16; ++it) {
            int u = it * 512 + tid;
            int f = u >> 6, c = u & 63;
            *(uint4*)(Bs + f * 512 + ((c ^ (f & 7)) << 3)) =
                *(const uint4*)(Bcg + (size_t)f * NG + (c << 3));
        }
        __syncthreads();
        f32x4 acc[8];
        #pragma unroll
        for (int ct = 0; ct < 8; ++ct) acc[ct] = (f32x4){0.f, 0.f, 0.f, 0.f};
        #pragma unroll 4
        for (int ks = 0; ks < 16; ++ks) {
            s16x8 a = *(const s16x8*)(Sg + ks * 32 + hi * 8);
            #pragma unroll
            for (int ct = 0; ct < 8; ++ct) {
                int col = ct * 16 + l15;
                s16x8 b = *(const s16x8*)(Bs + col * 512 + ((((ks << 2) | hi) ^ bxor) << 3));
                acc[ct] = __builtin_amdgcn_mfma_f32_16x16x32_bf16(a, b, acc[ct], 0, 0, 0);
            }
        }
        unsigned short* Tcg = Tc + (size_t)g * F * NG + rt * 128 + rloc;
        #pragma unroll
        for (int ct = 0; ct < 8; ++ct) {
            int col = ct * 16 + l15;
            uint2 w;
            w.x = pack16(acc[ct][0], acc[ct][1]);
            w.y = pack16(acc[ct][2], acc[ct][3]);
            *(uint2*)(Tcg + (size_t)col * NG) = w;
            #pragma unroll
            for (int r = 0; r < 4; ++r) {
                int row = rloc + r;
                Tt[row * F + ((((col >> 3) ^ (row & 15)) << 3) | (col & 7))] = f2bf(acc[ct][r]);
            }
        }
    }

    // ---- software grid barrier (Tc must be device-visible) ----
    __syncthreads();
    __threadfence();
    if (tid == 0) {
        __hip_atomic_fetch_add(barctr, 1u, __ATOMIC_ACQ_REL, __HIP_MEMORY_SCOPE_AGENT);
        while (__hip_atomic_load(barctr, __ATOMIC_ACQUIRE, __HIP_MEMORY_SCOPE_AGENT) <
               (unsigned)gridDim.x)
            __builtin_amdgcn_s_sleep(2);
    }
    __syncthreads();
    __threadfence();

    // ---- phase B: hop 2 ----
    {
        const unsigned short* Tcg = Tc + (size_t)g * F * NG;
        #pragma unroll
        for (int it = 0; it < 16; ++it) {
            int u = it * 512 + tid;
            int f = u >> 6, c = u & 63;
            *(uint4*)(Bs + f * 512 + ((c ^ (f & 7)) << 3)) =
                *(const uint4*)(Tcg + (size_t)f * NG + (c << 3));
        }
        __syncthreads();
        f32x4 sacc[8];
        #pragma unroll
        for (int ct = 0; ct < 8; ++ct) sacc[ct] = (f32x4){0.f, 0.f, 0.f, 0.f};
        #pragma unroll 4
        for (int ks = 0; ks < 16; ++ks) {
            s16x8 a = *(const s16x8*)(Sg + ks * 32 + hi * 8);
            #pragma unroll
            for (int ct = 0; ct < 8; ++ct) {
                int col = ct * 16 + l15;
                s16x8 b = *(const s16x8*)(Bs + col * 512 + ((((ks << 2) | hi) ^ bxor) << 3));
                sacc[ct] = __builtin_amdgcn_mfma_f32_16x16x32_bf16(a, b, sacc[ct], 0, 0, 0);
            }
        }
        __syncthreads();   // Bs reads done; reuse as t2 tile [128][136]
        #pragma unroll
        for (int ct = 0; ct < 8; ++ct) {
            int col = ct * 16 + l15;
            #pragma unroll
            for (int r = 0; r < 4; ++r)
                Bs[(rloc + r) * 136 + col] = f2bf(sacc[ct][r]);
        }
    }
    __syncthreads();

    // ---- conv: h = A0@W0 + t1@W1 + t2@W2 ----
    f32x4 acc[8];
    #pragma unroll
    for (int ct = 0; ct < 8; ++ct) acc[ct] = (f32x4){0.f, 0.f, 0.f, 0.f};
    const unsigned short* A0g = A0r + ((size_t)g * NG + rt * 128 + lrow) * F;
    #pragma unroll
    for (int ks = 0; ks < 12; ++ks) {
        s16x8 a;
        if (ks < 4) {
            a = *(const s16x8*)(A0g + ks * 32 + hi * 8);
        } else if (ks < 8) {
            int c8 = (ks - 4) * 4 + hi;
            a = *(const s16x8*)(Tt + lrow * F + ((c8 ^ (lrow & 15)) << 3));
        } else {
            a = *(const s16x8*)(Bs + lrow * 136 + (ks - 8) * 32 + hi * 8);
        }
        const unsigned short* wb = Wswz + ((size_t)ks * 512 + lane) * 8;
        #pragma unroll
        for (int ct = 0; ct < 8; ++ct) {
            s16x8 b = *(const s16x8*)(wb + (size_t)ct * 512);
            acc[ct] = __builtin_amdgcn_mfma_f32_16x16x32_bf16(a, b, acc[ct], 0, 0, 0);
        }
    }

    if (WRITE_H) {
        unsigned short* OutS = Bs + 40960;   // disjoint from t2 tile [0,17408)
        #pragma unroll
        for (int ct = 0; ct < 8; ++ct) {
            int col = ct * 16 + l15;
            float b = bias[col];
            float v0 = fmaxf(acc[ct][0] + b, 0.f);
            float v1 = fmaxf(acc[ct][1] + b, 0.f);
            float v2 = fmaxf(acc[ct][2] + b, 0.f);
            float v3 = fmaxf(acc[ct][3] + b, 0.f);
            uint2 w;
            w.x = pack16(v0, v1);
            w.y = pack16(v2, v3);
            *(uint2*)(Hc + (size_t)g * F * NG + (size_t)col * NG + rt * 128 + rloc) = w;
            OutS[(rloc + 0) * F + col] = f2bf(v0);
            OutS[(rloc + 1) * F + col] = f2bf(v1);
            OutS[(rloc + 2) * F + col] = f2bf(v2);
            OutS[(rloc + 3) * F + col] = f2bf(v3);
        }
        __syncthreads();
        uint4* o4 = (uint4*)(Hr + ((size_t)g * NG + rt * 128) * F);
        const uint4* s4 = (const uint4*)OutS;
        #pragma unroll
        for (int u = tid; u < 128 * F / 8; u += 512) o4[u] = s4[u];
    } else {
        __syncthreads();   // t2-tile reads done before aliasing with wmax
        float* wmax = (float*)Bs;
        #pragma unroll
        for (int ct = 0; ct < 8; ++ct) {
            int col = ct * 16 + l15;
            float b = bias[col];
            float m = fmaxf(fmaxf(acc[ct][0], acc[ct][1]), fmaxf(acc[ct][2], acc[ct][3]));
            m = fmaxf(m + b, 0.f);
            m = fmaxf(m, __shfl_xor(m, 16));
            m = fmaxf(m, __shfl_xor(m, 32));
            if (lane < 16) wmax[wave * F + col] = m;
        }
        __syncthreads();
        if (tid < F) {
            float m = wmax[tid];
            #pragma unroll
            for (int w = 1; w < 8; ++w) m = fmaxf(m, wmax[w * F + tid]);
            pooledp[((size_t)rt * 64 + g) * F + tid] = m;
        }
    }
}

// ---------------- output head: pooled = max over 4 partials; out = pooled @ Wout + bout ----

__global__ __launch_bounds__(64) void out_gemm_kernel(const float* __restrict__ pooledp,
                                                      const float* __restrict__ Wout,
                                                      const float* __restrict__ bout,
                                                      float* __restrict__ out) {
    __shared__ float p[F];
    int b = blockIdx.x, t = threadIdx.x;
    #pragma unroll
    for (int c = t; c < F; c += 64) {
        float m = pooledp[(size_t)b * F + c];
        m = fmaxf(m, pooledp[((size_t)64 + b) * F + c]);
        m = fmaxf(m, pooledp[((size_t)128 + b) * F + c]);
        m = fmaxf(m, pooledp[((size_t)192 + b) * F + c]);
        p[c] = m;
    }
    __syncthreads();
    float acc = bout[t];
    #pragma unroll 8
    for (int k = 0; k < F; ++k) acc += p[k] * Wout[k * 64 + t];
    out[(size_t)b * 64 + t] = acc;
}

// ---------------- launch ----------------

extern "C" void kernel_launch(void* const* d_in, const int* in_sizes, int n_in,
                              void* d_out, int out_size, void* d_ws, size_t ws_size,
                              hipStream_t stream) {
    const float* X     = (const float*)d_in[0];
    const int*   ei    = (const int*)d_in[2];
    const float* W1    = (const float*)d_in[3];
    const float* b1    = (const float*)d_in[4];
    const float* W2    = (const float*)d_in[5];
    const float* b2    = (const float*)d_in[6];
    const float* Wout  = (const float*)d_in[7];
    const float* bout  = (const float*)d_in[8];
    const float* alpha = (const float*)d_in[9];

    const int N = in_sizes[0] / F;   // 32768
    const int E = in_sizes[2] / 2;   // 524288
    const int Bg = N / NG;           // 64

    const int* srcv = ei;
    const int* dstv = ei + E;

    char* ws = (char*)d_ws;
    const size_t SBYTES = (size_t)Bg * NG * NG * 2;   // 33.55 MB
    const size_t PBYTES = (size_t)N * F * 2;          // 8.39 MB

    unsigned short* Sb = (unsigned short*)ws;
    unsigned short* P0 = (unsigned short*)(ws + SBYTES);               // Xr -> h1r
    unsigned short* P1 = (unsigned short*)(ws + SBYTES + PBYTES);      // Xc -> h1c
    unsigned short* P3 = (unsigned short*)(ws + SBYTES + 2 * PBYTES);  // t1c / u1c
    char* tail = ws + SBYTES + 3 * PBYTES;
    unsigned short* Wswz1 = (unsigned short*)tail;
    unsigned short* Wswz2 = Wswz1 + (size_t)3 * F * F;
    float* pooledp = (float*)(Wswz2 + (size_t)3 * F * F);             // [4][64][128]
    unsigned int* barctr = (unsigned int*)((char*)(pooledp + 4 * 64 * F));  // 256 B
    unsigned int* cnt32 = barctr + 64;                                 // 16.78 MB

    // prep (cast + both weight shuffles) || zero {barrier counters, edge counters}
    prep_kernel<<<896, 256, 0, stream>>>(X, P0, P1, W1, W2, Wswz1, Wswz2);
    hipMemsetAsync(barctr, 0, 256 + (size_t)Bg * NG * NG, stream);

    // dense S build
    cnt_scatter_kernel<<<(E + 255) / 256, 256, 0, stream>>>(srcv, dstv, cnt32, E);
    sgen_kernel<<<(Bg * NG * NG / 8) / 256, 256, 0, stream>>>((const unsigned char*)cnt32, Sb, alpha);

    // layer 1: t1 = S@X ; h1 = relu(X@W0 + t1@W1 + (S@t1)@W2 + b1) -> P0 (row), P1 (col)
    layer_kernel<1><<<Bg * 4, 512, 0, stream>>>(Sb, P1, P0, P3, Wswz1, b1, P0, P1, nullptr, barctr);

    // layer 2: u1 = S@h1 ; pooledp = blockwise colmax(relu(h1@W0 + u1@W1 + (S@u1)@W2 + b2))
    layer_kernel<0><<<Bg * 4, 512, 0, stream>>>(Sb, P1, P0, P3, Wswz2, b2, nullptr, nullptr, pooledp, barctr + 32);

    // head
    out_gemm_kernel<<<Bg, 64, 0, stream>>>(pooledp, Wout, bout, (float*)d_out);
}

// Round 8
// 177.533 us; speedup vs baseline: 1.5453x; 1.5453x over previous
//
#include <hip/hip_runtime.h>
#include <hip/hip_bf16.h>

#define F 128
#define NG 512

typedef __attribute__((ext_vector_type(8))) short s16x8;
typedef __attribute__((ext_vector_type(4))) float f32x4;
typedef __attribute__((ext_vector_type(16))) float f32x16;

__device__ inline float bf2f(unsigned short u) {
    unsigned int x = ((unsigned int)u) << 16;
    return __builtin_bit_cast(float, x);
}
__device__ inline unsigned short f2bf(float f) {
    __hip_bfloat16 h = __float2bfloat16(f);
    return __builtin_bit_cast(unsigned short, h);
}
__device__ inline unsigned int pack16(float x, float y) {
    return (unsigned int)f2bf(x) | ((unsigned int)f2bf(y) << 16);
}

// ---------------- prep: cast X (f32->bf16 row+col major) and shuffle weights ----------------

__global__ __launch_bounds__(256) void prep_kernel(const float* __restrict__ X,
                                                   unsigned short* __restrict__ Xr,
                                                   unsigned short* __restrict__ Xc,
                                                   const float* __restrict__ W1,
                                                   const float* __restrict__ W2,
                                                   unsigned short* __restrict__ o1,
                                                   unsigned short* __restrict__ o2) {
    __shared__ unsigned short tile[64][F + 4];
    int tid = threadIdx.x;
    if (blockIdx.x < 512) {
        int g = blockIdx.x >> 3;
        int nt = blockIdx.x & 7;
        int node0 = nt * 64;
        const float* Xg = X + ((size_t)g * NG + node0) * F;
        unsigned short* Xrg = Xr + ((size_t)g * NG + node0) * F;
        #pragma unroll
        for (int u = tid; u < 64 * 32; u += 256) {
            int row = u >> 5, c4 = u & 31;
            float4 v = ((const float4*)(Xg + (size_t)row * F))[c4];
            unsigned short a0 = f2bf(v.x), a1 = f2bf(v.y), a2 = f2bf(v.z), a3 = f2bf(v.w);
            tile[row][c4 * 4 + 0] = a0;
            tile[row][c4 * 4 + 1] = a1;
            tile[row][c4 * 4 + 2] = a2;
            tile[row][c4 * 4 + 3] = a3;
            uint2 w;
            w.x = (unsigned int)a0 | ((unsigned int)a1 << 16);
            w.y = (unsigned int)a2 | ((unsigned int)a3 << 16);
            ((uint2*)(Xrg + (size_t)row * F))[c4] = w;
        }
        __syncthreads();
        unsigned short* Xcg = Xc + (size_t)g * F * NG;
        #pragma unroll
        for (int u = tid; u < F * 16; u += 256) {
            int f = u >> 4, nb = u & 15;
            int n0 = nb * 4;
            uint2 w;
            w.x = (unsigned int)tile[n0 + 0][f] | ((unsigned int)tile[n0 + 1][f] << 16);
            w.y = (unsigned int)tile[n0 + 2][f] | ((unsigned int)tile[n0 + 3][f] << 16);
            ((uint2*)(Xcg + (size_t)f * NG + node0))[nb] = w;
        }
    } else {
        int t = (blockIdx.x - 512) * 256 + tid;   // [0, 98304)
        const float* W = (t < 49152) ? W1 : W2;
        unsigned short* o = (t < 49152) ? o1 : o2;
        int tt = (t < 49152) ? t : t - 49152;
        int j = tt & 7;
        int lane = (tt >> 3) & 63;
        int ct = (tt >> 9) & 7;
        int ks = tt >> 12;
        int k = ks * 32 + (lane >> 4) * 8 + j;
        int c = ct * 16 + (lane & 15);
        o[tt] = f2bf(W[(size_t)k * F + c]);
    }
}

// ---------------- dense S build ----------------

__global__ void cnt_scatter_kernel(const int* __restrict__ src, const int* __restrict__ dst,
                                   unsigned int* __restrict__ cnt32, int E) {
    int e = blockIdx.x * blockDim.x + threadIdx.x;
    if (e >= E) return;
    int s = src[e], d = dst[e];
    size_t idx = ((size_t)s << 9) | (unsigned)(d & (NG - 1));
    atomicAdd(&cnt32[idx >> 2], 1u << ((idx & 3) * 8));
}

__global__ __launch_bounds__(256) void sgen_kernel(const unsigned char* __restrict__ cnt,
                                                   unsigned short* __restrict__ Sb,
                                                   const float* __restrict__ alphap) {
    size_t t = (size_t)blockIdx.x * 256 + threadIdx.x;
    size_t base = t * 8;
    float alpha = *alphap;
    float diag = 1.0f - alpha;
    int i = (int)((base >> 9) & (NG - 1));
    int j0 = (int)(base & (NG - 1));
    uint2 c = *(const uint2*)(cnt + base);
    unsigned short o[8];
    #pragma unroll
    for (int b = 0; b < 8; ++b) {
        unsigned cv = ((b < 4) ? (c.x >> (8 * b)) : (c.y >> (8 * (b - 4)))) & 0xffu;
        float v = alpha * (float)cv + ((i == j0 + b) ? diag : 0.f);
        o[b] = f2bf(v);
    }
    uint4 w;
    w.x = (unsigned int)o[0] | ((unsigned int)o[1] << 16);
    w.y = (unsigned int)o[2] | ((unsigned int)o[3] << 16);
    w.z = (unsigned int)o[4] | ((unsigned int)o[5] << 16);
    w.w = (unsigned int)o[6] | ((unsigned int)o[7] << 16);
    *(uint4*)(Sb + base) = w;
}

// ---------------- S-apply (32x32x16 MFMA): C[g] = S[g] @ B[g] ----------------
// 8 waves; wave = (cg = w&3 col-group of 32, rp = w>>2 row-pair base 64) -> two 32x32 tiles
// sharing one b-frag per K-step. B staged in LDS (chunk-XOR swizzled). S streamed from global.

__global__ __launch_bounds__(512) void sapply_kernel(
    const unsigned short* __restrict__ S, const unsigned short* __restrict__ Bc,
    unsigned short* __restrict__ Cr, unsigned short* __restrict__ Cc) {
    __shared__ unsigned short Bs[65536];   // 128 KB
    const int g = blockIdx.x >> 2, rt = blockIdx.x & 3;
    const int tid = threadIdx.x, wave = tid >> 6, lane = tid & 63;
    const int l31 = lane & 31, hi5 = lane >> 5;
    const int cg = wave & 3;
    const int R0 = (wave >> 2) * 64;
    const int col = cg * 32 + l31;
    const int cx = l31 & 7;

    const unsigned short* Bcg = Bc + (size_t)g * F * NG;
    #pragma unroll
    for (int it = 0; it < 16; ++it) {
        int u = it * 512 + tid;
        int f = u >> 6, c = u & 63;
        *(uint4*)(Bs + f * 512 + ((c ^ (f & 7)) << 3)) =
            *(const uint4*)(Bcg + (size_t)f * NG + (c << 3));
    }
    __syncthreads();

    f32x16 accA, accB;
    #pragma unroll
    for (int i = 0; i < 16; ++i) { accA[i] = 0.f; accB[i] = 0.f; }

    const unsigned short* SgA = S + ((size_t)g * NG + rt * 128 + R0 + l31) * NG;
    #pragma unroll 8
    for (int ks = 0; ks < 32; ++ks) {
        s16x8 a0 = *(const s16x8*)(SgA + ks * 16 + hi5 * 8);
        s16x8 a1 = *(const s16x8*)(SgA + (size_t)32 * NG + ks * 16 + hi5 * 8);
        s16x8 b = *(const s16x8*)(Bs + col * 512 + ((((ks << 1) | hi5) ^ cx) << 3));
        accA = __builtin_amdgcn_mfma_f32_32x32x16_bf16(a0, b, accA, 0, 0, 0);
        accB = __builtin_amdgcn_mfma_f32_32x32x16_bf16(a1, b, accB, 0, 0, 0);
    }
    __syncthreads();   // Bs reads done; safe to reuse

    // epilogue: col-major direct + row-major via LDS staging
    unsigned short* OutS = Bs + 40960;
    unsigned short* Ccg = Cc + (size_t)g * F * NG + (size_t)col * NG + rt * 128;
    #pragma unroll
    for (int tt = 0; tt < 2; ++tt) {
        f32x16 acc = tt ? accB : accA;
        int rowb = R0 + tt * 32 + hi5 * 4;
        #pragma unroll
        for (int q = 0; q < 4; ++q) {
            float v0 = acc[4 * q + 0], v1 = acc[4 * q + 1];
            float v2 = acc[4 * q + 2], v3 = acc[4 * q + 3];
            uint2 w;
            w.x = pack16(v0, v1);
            w.y = pack16(v2, v3);
            *(uint2*)(Ccg + rowb + q * 8) = w;
            OutS[(rowb + q * 8 + 0) * F + col] = f2bf(v0);
            OutS[(rowb + q * 8 + 1) * F + col] = f2bf(v1);
            OutS[(rowb + q * 8 + 2) * F + col] = f2bf(v2);
            OutS[(rowb + q * 8 + 3) * F + col] = f2bf(v3);
        }
    }
    __syncthreads();
    uint4* o4 = (uint4*)(Cr + ((size_t)g * NG + rt * 128) * F);
    const uint4* s4 = (const uint4*)OutS;
    #pragma unroll
    for (int u = tid; u < 128 * F / 8; u += 512) o4[u] = s4[u];
}

// ---------------- fused: t2 = S@Bc (32x32 MFMA, LDS-staged B) -> t2 tile -> conv (16x16) ----
// WRITE_H=1: h -> Hr (row) + Hc (col).  WRITE_H=0: per-block col max -> pooledp[rt][g][F].

template <int WRITE_H>
__global__ __launch_bounds__(512) void fused_conv_kernel(
    const unsigned short* __restrict__ S, const unsigned short* __restrict__ Bc,
    const unsigned short* __restrict__ A0, const unsigned short* __restrict__ A1,
    const unsigned short* __restrict__ Wswz, const float* __restrict__ bias,
    unsigned short* __restrict__ Hr, unsigned short* __restrict__ Hc,
    float* __restrict__ pooledp) {
    __shared__ unsigned short Bs[65536];   // 128 KB: B stage -> t2 tile [128][136] -> epilogue
    const int g = blockIdx.x >> 2, rt = blockIdx.x & 3;
    const int tid = threadIdx.x, wave = tid >> 6, lane = tid & 63;
    const int l31 = lane & 31, hi5 = lane >> 5;
    const int l15 = lane & 15, hi = lane >> 4;
    const int lrow = wave * 16 + l15;

    const unsigned short* Bcg = Bc + (size_t)g * F * NG;
    #pragma unroll
    for (int it = 0; it < 16; ++it) {
        int u = it * 512 + tid;
        int f = u >> 6, c = u & 63;
        *(uint4*)(Bs + f * 512 + ((c ^ (f & 7)) << 3)) =
            *(const uint4*)(Bcg + (size_t)f * NG + (c << 3));
    }
    __syncthreads();

    // ---- S-phase (32x32x16): t2 tile = S(rows) @ B ----
    {
        const int cg = wave & 3;
        const int R0 = (wave >> 2) * 64;
        const int col = cg * 32 + l31;
        const int cx = l31 & 7;
        f32x16 accA, accB;
        #pragma unroll
        for (int i = 0; i < 16; ++i) { accA[i] = 0.f; accB[i] = 0.f; }
        const unsigned short* SgA = S + ((size_t)g * NG + rt * 128 + R0 + l31) * NG;
        #pragma unroll 8
        for (int ks = 0; ks < 32; ++ks) {
            s16x8 a0 = *(const s16x8*)(SgA + ks * 16 + hi5 * 8);
            s16x8 a1 = *(const s16x8*)(SgA + (size_t)32 * NG + ks * 16 + hi5 * 8);
            s16x8 b = *(const s16x8*)(Bs + col * 512 + ((((ks << 1) | hi5) ^ cx) << 3));
            accA = __builtin_amdgcn_mfma_f32_32x32x16_bf16(a0, b, accA, 0, 0, 0);
            accB = __builtin_amdgcn_mfma_f32_32x32x16_bf16(a1, b, accB, 0, 0, 0);
        }
        __syncthreads();   // B reads complete; reuse Bs[0..17408) as t2 tile [128][136]
        #pragma unroll
        for (int tt = 0; tt < 2; ++tt) {
            f32x16 acc = tt ? accB : accA;
            int rowb = R0 + tt * 32 + hi5 * 4;
            #pragma unroll
            for (int q = 0; q < 4; ++q) {
                #pragma unroll
                for (int r = 0; r < 4; ++r)
                    Bs[(rowb + q * 8 + r) * 136 + col] = f2bf(acc[4 * q + r]);
            }
        }
    }
    __syncthreads();

    // ---- conv phase (16x16x32): h = A0@W0 + A1@W1 + t2@W2 ----
    f32x4 acc[8];
    #pragma unroll
    for (int ct = 0; ct < 8; ++ct) acc[ct] = (f32x4){0.f, 0.f, 0.f, 0.f};
    const int arow = blockIdx.x * 128 + lrow;
    #pragma unroll
    for (int ks = 0; ks < 12; ++ks) {
        s16x8 a;
        if (ks < 4) {
            a = *(const s16x8*)(A0 + (size_t)arow * F + ks * 32 + hi * 8);
        } else if (ks < 8) {
            a = *(const s16x8*)(A1 + (size_t)arow * F + (ks - 4) * 32 + hi * 8);
        } else {
            a = *(const s16x8*)(Bs + lrow * 136 + (ks - 8) * 32 + hi * 8);
        }
        const unsigned short* wb = Wswz + ((size_t)ks * 512 + lane) * 8;
        #pragma unroll
        for (int ct = 0; ct < 8; ++ct) {
            s16x8 b = *(const s16x8*)(wb + (size_t)ct * 512);
            acc[ct] = __builtin_amdgcn_mfma_f32_16x16x32_bf16(a, b, acc[ct], 0, 0, 0);
        }
    }

    const int rloc = wave * 16 + (hi << 2);
    if (WRITE_H) {
        unsigned short* OutS = Bs + 40960;   // disjoint from t2 tile [0,17408)
        #pragma unroll
        for (int ct = 0; ct < 8; ++ct) {
            int col = ct * 16 + l15;
            float b = bias[col];
            float v0 = fmaxf(acc[ct][0] + b, 0.f);
            float v1 = fmaxf(acc[ct][1] + b, 0.f);
            float v2 = fmaxf(acc[ct][2] + b, 0.f);
            float v3 = fmaxf(acc[ct][3] + b, 0.f);
            uint2 w;
            w.x = pack16(v0, v1);
            w.y = pack16(v2, v3);
            *(uint2*)(Hc + (size_t)g * F * NG + (size_t)col * NG + rt * 128 + rloc) = w;
            OutS[(rloc + 0) * F + col] = f2bf(v0);
            OutS[(rloc + 1) * F + col] = f2bf(v1);
            OutS[(rloc + 2) * F + col] = f2bf(v2);
            OutS[(rloc + 3) * F + col] = f2bf(v3);
        }
        __syncthreads();
        uint4* o4 = (uint4*)(Hr + ((size_t)g * NG + rt * 128) * F);
        const uint4* s4 = (const uint4*)OutS;
        #pragma unroll
        for (int u = tid; u < 128 * F / 8; u += 512) o4[u] = s4[u];
    } else {
        __syncthreads();   // t2-tile reads done before aliasing with wmax
        float* wmax = (float*)Bs;
        #pragma unroll
        for (int ct = 0; ct < 8; ++ct) {
            int col = ct * 16 + l15;
            float b = bias[col];
            float m = fmaxf(fmaxf(acc[ct][0], acc[ct][1]), fmaxf(acc[ct][2], acc[ct][3]));
            m = fmaxf(m + b, 0.f);
            m = fmaxf(m, __shfl_xor(m, 16));
            m = fmaxf(m, __shfl_xor(m, 32));
            if (lane < 16) wmax[wave * F + col] = m;
        }
        __syncthreads();
        if (tid < F) {
            float m = wmax[tid];
            #pragma unroll
            for (int w = 1; w < 8; ++w) m = fmaxf(m, wmax[w * F + tid]);
            pooledp[((size_t)rt * 64 + g) * F + tid] = m;
        }
    }
}

// ---------------- output head: pooled = max over 4 partials; out = pooled @ Wout + bout ----

__global__ __launch_bounds__(64) void out_gemm_kernel(const float* __restrict__ pooledp,
                                                      const float* __restrict__ Wout,
                                                      const float* __restrict__ bout,
                                                      float* __restrict__ out) {
    __shared__ float p[F];
    int b = blockIdx.x, t = threadIdx.x;
    #pragma unroll
    for (int c = t; c < F; c += 64) {
        float m = pooledp[(size_t)b * F + c];
        m = fmaxf(m, pooledp[((size_t)64 + b) * F + c]);
        m = fmaxf(m, pooledp[((size_t)128 + b) * F + c]);
        m = fmaxf(m, pooledp[((size_t)192 + b) * F + c]);
        p[c] = m;
    }
    __syncthreads();
    float acc = bout[t];
    #pragma unroll 8
    for (int k = 0; k < F; ++k) acc += p[k] * Wout[k * 64 + t];
    out[(size_t)b * 64 + t] = acc;
}

// ---------------- launch ----------------

extern "C" void kernel_launch(void* const* d_in, const int* in_sizes, int n_in,
                              void* d_out, int out_size, void* d_ws, size_t ws_size,
                              hipStream_t stream) {
    const float* X     = (const float*)d_in[0];
    const int*   ei    = (const int*)d_in[2];
    const float* W1    = (const float*)d_in[3];
    const float* b1    = (const float*)d_in[4];
    const float* W2    = (const float*)d_in[5];
    const float* b2    = (const float*)d_in[6];
    const float* Wout  = (const float*)d_in[7];
    const float* bout  = (const float*)d_in[8];
    const float* alpha = (const float*)d_in[9];

    const int N = in_sizes[0] / F;   // 32768
    const int E = in_sizes[2] / 2;   // 524288
    const int Bg = N / NG;           // 64

    const int* srcv = ei;
    const int* dstv = ei + E;

    char* ws = (char*)d_ws;
    const size_t SBYTES = (size_t)Bg * NG * NG * 2;   // 33.55 MB
    const size_t PBYTES = (size_t)N * F * 2;          // 8.39 MB

    unsigned short* Sb = (unsigned short*)ws;
    unsigned short* P0 = (unsigned short*)(ws + SBYTES);               // Xr -> h1r
    unsigned short* P1 = (unsigned short*)(ws + SBYTES + PBYTES);      // Xc -> h1c
    unsigned short* P2 = (unsigned short*)(ws + SBYTES + 2 * PBYTES);  // t1r / u1r
    unsigned short* P3 = (unsigned short*)(ws + SBYTES + 3 * PBYTES);  // t1c / u1c
    char* tail = ws + SBYTES + 4 * PBYTES;
    unsigned short* Wswz1 = (unsigned short*)tail;
    unsigned short* Wswz2 = Wswz1 + (size_t)3 * F * F;
    float* pooledp = (float*)(Wswz2 + (size_t)3 * F * F);             // [4][64][128]
    // cnt aliases P2+P3 (exactly 16.78 MB); consumed by sgen before sapply writes P2/P3
    unsigned int* cnt32 = (unsigned int*)P2;

    // prep (cast + both weight shuffles) || zero edge counters
    prep_kernel<<<896, 256, 0, stream>>>(X, P0, P1, W1, W2, Wswz1, Wswz2);
    hipMemsetAsync(cnt32, 0, (size_t)Bg * NG * NG, stream);

    // dense S build
    cnt_scatter_kernel<<<(E + 255) / 256, 256, 0, stream>>>(srcv, dstv, cnt32, E);
    sgen_kernel<<<(Bg * NG * NG / 8) / 256, 256, 0, stream>>>((const unsigned char*)cnt32, Sb, alpha);

    // layer 1: t1 = S@X ; h1 = relu(X@W0 + t1@W1 + (S@t1)@W2 + b1)
    sapply_kernel<<<Bg * 4, 512, 0, stream>>>(Sb, P1, P2, P3);
    fused_conv_kernel<1><<<Bg * 4, 512, 0, stream>>>(Sb, P3, P0, P2, Wswz1, b1, P0, P1, nullptr);

    // layer 2: u1 = S@h1 ; pooledp = blockwise colmax(relu(h1@W0 + u1@W1 + (S@u1)@W2 + b2))
    sapply_kernel<<<Bg * 4, 512, 0, stream>>>(Sb, P1, P2, P3);
    fused_conv_kernel<0><<<Bg * 4, 512, 0, stream>>>(Sb, P3, P0, P2, Wswz2, b2, nullptr, nullptr, pooledp);

    // head
    out_gemm_kernel<<<Bg, 64, 0, stream>>>(pooledp, Wout, bout, (float*)d_out);
}

// Round 9
// 137.129 us; speedup vs baseline: 2.0007x; 1.2946x over previous
//
#include <hip/hip_runtime.h>
#include <hip/hip_bf16.h>

#define F 128
#define NG 512

typedef __attribute__((ext_vector_type(8))) short s16x8;
typedef __attribute__((ext_vector_type(4))) float f32x4;

__device__ inline float bf2f(unsigned short u) {
    unsigned int x = ((unsigned int)u) << 16;
    return __builtin_bit_cast(float, x);
}
__device__ inline unsigned short f2bf(float f) {
    __hip_bfloat16 h = __float2bfloat16(f);
    return __builtin_bit_cast(unsigned short, h);
}
__device__ inline unsigned int pack16(float x, float y) {
    return (unsigned int)f2bf(x) | ((unsigned int)f2bf(y) << 16);
}

// ---- prep: cast X (row+col major bf16) + shuffle weights + zero edge counters ----
// blocks [0,512): X cast; [512,896): weight shuffle; [896,1920): zero cnt (16.78 MB)

__global__ __launch_bounds__(256) void prep_kernel(const float* __restrict__ X,
                                                   unsigned short* __restrict__ Xr,
                                                   unsigned short* __restrict__ Xc,
                                                   const float* __restrict__ W1,
                                                   const float* __restrict__ W2,
                                                   unsigned short* __restrict__ o1,
                                                   unsigned short* __restrict__ o2,
                                                   uint4* __restrict__ cntz) {
    __shared__ unsigned short tile[64][F + 4];
    int tid = threadIdx.x;
    if (blockIdx.x < 512) {
        int g = blockIdx.x >> 3;
        int nt = blockIdx.x & 7;
        int node0 = nt * 64;
        const float* Xg = X + ((size_t)g * NG + node0) * F;
        unsigned short* Xrg = Xr + ((size_t)g * NG + node0) * F;
        #pragma unroll
        for (int u = tid; u < 64 * 32; u += 256) {
            int row = u >> 5, c4 = u & 31;
            float4 v = ((const float4*)(Xg + (size_t)row * F))[c4];
            unsigned short a0 = f2bf(v.x), a1 = f2bf(v.y), a2 = f2bf(v.z), a3 = f2bf(v.w);
            tile[row][c4 * 4 + 0] = a0;
            tile[row][c4 * 4 + 1] = a1;
            tile[row][c4 * 4 + 2] = a2;
            tile[row][c4 * 4 + 3] = a3;
            uint2 w;
            w.x = (unsigned int)a0 | ((unsigned int)a1 << 16);
            w.y = (unsigned int)a2 | ((unsigned int)a3 << 16);
            ((uint2*)(Xrg + (size_t)row * F))[c4] = w;
        }
        __syncthreads();
        unsigned short* Xcg = Xc + (size_t)g * F * NG;
        #pragma unroll
        for (int u = tid; u < F * 16; u += 256) {
            int f = u >> 4, nb = u & 15;
            int n0 = nb * 4;
            uint2 w;
            w.x = (unsigned int)tile[n0 + 0][f] | ((unsigned int)tile[n0 + 1][f] << 16);
            w.y = (unsigned int)tile[n0 + 2][f] | ((unsigned int)tile[n0 + 3][f] << 16);
            ((uint2*)(Xcg + (size_t)f * NG + node0))[nb] = w;
        }
    } else if (blockIdx.x < 896) {
        int t = (blockIdx.x - 512) * 256 + tid;   // [0, 98304)
        const float* W = (t < 49152) ? W1 : W2;
        unsigned short* o = (t < 49152) ? o1 : o2;
        int tt = (t < 49152) ? t : t - 49152;
        int j = tt & 7;
        int lane = (tt >> 3) & 63;
        int ct = (tt >> 9) & 7;
        int ks = tt >> 12;
        int k = ks * 32 + (lane >> 4) * 8 + j;
        int c = ct * 16 + (lane & 15);
        o[tt] = f2bf(W[(size_t)k * F + c]);
    } else {
        // zero 16.78 MB of cnt: 1024 blocks x 256 thr x 4 uint4
        size_t base = (size_t)(blockIdx.x - 896) * 1024;
        uint4 z = {0u, 0u, 0u, 0u};
        #pragma unroll
        for (int i = 0; i < 4; ++i) cntz[base + i * 256 + tid] = z;
    }
}

// ---------------- dense S build ----------------

__global__ void cnt_scatter_kernel(const int* __restrict__ src, const int* __restrict__ dst,
                                   unsigned int* __restrict__ cnt32, int E) {
    int e = blockIdx.x * blockDim.x + threadIdx.x;
    if (e >= E) return;
    int s = src[e], d = dst[e];
    size_t idx = ((size_t)s << 9) | (unsigned)(d & (NG - 1));
    atomicAdd(&cnt32[idx >> 2], 1u << ((idx & 3) * 8));
}

__global__ __launch_bounds__(256) void sgen_kernel(const unsigned char* __restrict__ cnt,
                                                   unsigned short* __restrict__ Sb,
                                                   const float* __restrict__ alphap) {
    size_t t = (size_t)blockIdx.x * 256 + threadIdx.x;
    size_t base = t * 8;
    float alpha = *alphap;
    float diag = 1.0f - alpha;
    int i = (int)((base >> 9) & (NG - 1));
    int j0 = (int)(base & (NG - 1));
    uint2 c = *(const uint2*)(cnt + base);
    unsigned short o[8];
    #pragma unroll
    for (int b = 0; b < 8; ++b) {
        unsigned cv = ((b < 4) ? (c.x >> (8 * b)) : (c.y >> (8 * (b - 4)))) & 0xffu;
        float v = alpha * (float)cv + ((i == j0 + b) ? diag : 0.f);
        o[b] = f2bf(v);
    }
    uint4 w;
    w.x = (unsigned int)o[0] | ((unsigned int)o[1] << 16);
    w.y = (unsigned int)o[2] | ((unsigned int)o[3] << 16);
    w.z = (unsigned int)o[4] | ((unsigned int)o[5] << 16);
    w.w = (unsigned int)o[6] | ((unsigned int)o[7] << 16);
    *(uint4*)(Sb + base) = w;
}

// ---------------- S-apply with B staged in LDS: C[g] = S[g] @ B[g] (16x16x32) ----------------
// B element [k][col] lives at Bs[col*512 + ((k>>3)^(col&7))*8 + (k&7)]  (chunk XOR swizzle).

__global__ __launch_bounds__(512) void sapply_kernel(
    const unsigned short* __restrict__ S, const unsigned short* __restrict__ Bc,
    unsigned short* __restrict__ Cr, unsigned short* __restrict__ Cc) {
    __shared__ unsigned short Bs[65536];   // 128 KB
    const int g = blockIdx.x >> 2, rt = blockIdx.x & 3;
    const int tid = threadIdx.x, wave = tid >> 6, lane = tid & 63;
    const int l15 = lane & 15, hi = lane >> 4;
    const int lrow = wave * 16 + l15;

    const unsigned short* Bcg = Bc + (size_t)g * F * NG;
    #pragma unroll
    for (int it = 0; it < 16; ++it) {
        int u = it * 512 + tid;
        int f = u >> 6, c = u & 63;
        *(uint4*)(Bs + f * 512 + ((c ^ (f & 7)) << 3)) =
            *(const uint4*)(Bcg + (size_t)f * NG + (c << 3));
    }
    __syncthreads();

    f32x4 acc[8];
    #pragma unroll
    for (int ct = 0; ct < 8; ++ct) acc[ct] = (f32x4){0.f, 0.f, 0.f, 0.f};

    const unsigned short* Sg = S + ((size_t)g * NG + rt * 128 + lrow) * NG;
    const int bxor = l15 & 7;
    #pragma unroll 4
    for (int ks = 0; ks < 16; ++ks) {
        s16x8 a = *(const s16x8*)(Sg + ks * 32 + hi * 8);
        #pragma unroll
        for (int ct = 0; ct < 8; ++ct) {
            int col = ct * 16 + l15;
            s16x8 b = *(const s16x8*)(Bs + col * 512 + ((((ks << 2) | hi) ^ bxor) << 3));
            acc[ct] = __builtin_amdgcn_mfma_f32_16x16x32_bf16(a, b, acc[ct], 0, 0, 0);
        }
    }
    __syncthreads();   // all waves done reading Bs; safe to reuse

    const int rloc = wave * 16 + (hi << 2);
    unsigned short* OutS = Bs + 40960;
    unsigned short* Ccg = Cc + (size_t)g * F * NG + rt * 128 + rloc;
    #pragma unroll
    for (int ct = 0; ct < 8; ++ct) {
        int col = ct * 16 + l15;
        uint2 w;
        w.x = pack16(acc[ct][0], acc[ct][1]);
        w.y = pack16(acc[ct][2], acc[ct][3]);
        *(uint2*)(Ccg + (size_t)col * NG) = w;
        #pragma unroll
        for (int r = 0; r < 4; ++r)
            OutS[(rloc + r) * F + col] = f2bf(acc[ct][r]);
    }
    __syncthreads();
    uint4* o4 = (uint4*)(Cr + ((size_t)g * NG + rt * 128) * F);
    const uint4* s4 = (const uint4*)OutS;
    #pragma unroll
    for (int u = tid; u < 128 * F / 8; u += 512) o4[u] = s4[u];
}

// ---------------- fused: t2 = S@Bc (LDS-staged B) -> t2 tile in LDS -> conv ----------------
// WRITE_H=1: h -> Hr (row) + Hc (col). WRITE_H=0: per-block col max -> pooledp[rt][g][F].

template <int WRITE_H>
__global__ __launch_bounds__(512) void fused_conv_kernel(
    const unsigned short* __restrict__ S, const unsigned short* __restrict__ Bc,
    const unsigned short* __restrict__ A0, const unsigned short* __restrict__ A1,
    const unsigned short* __restrict__ Wswz, const float* __restrict__ bias,
    unsigned short* __restrict__ Hr, unsigned short* __restrict__ Hc,
    float* __restrict__ pooledp) {
    __shared__ unsigned short Bs[65536];   // 128 KB; B stage -> t2 tile [128][136] -> epilogue
    const int g = blockIdx.x >> 2, rt = blockIdx.x & 3;
    const int tid = threadIdx.x, wave = tid >> 6, lane = tid & 63;
    const int l15 = lane & 15, hi = lane >> 4;
    const int lrow = wave * 16 + l15;

    const unsigned short* Bcg = Bc + (size_t)g * F * NG;
    #pragma unroll
    for (int it = 0; it < 16; ++it) {
        int u = it * 512 + tid;
        int f = u >> 6, c = u & 63;
        *(uint4*)(Bs + f * 512 + ((c ^ (f & 7)) << 3)) =
            *(const uint4*)(Bcg + (size_t)f * NG + (c << 3));
    }
    __syncthreads();

    // ---- S-phase: t2 tile = S(rows) @ B ----
    f32x4 sacc[8];
    #pragma unroll
    for (int ct = 0; ct < 8; ++ct) sacc[ct] = (f32x4){0.f, 0.f, 0.f, 0.f};
    {
        const unsigned short* Sg = S + ((size_t)g * NG + rt * 128 + lrow) * NG;
        const int bxor = l15 & 7;
        #pragma unroll 4
        for (int ks = 0; ks < 16; ++ks) {
            s16x8 a = *(const s16x8*)(Sg + ks * 32 + hi * 8);
            #pragma unroll
            for (int ct = 0; ct < 8; ++ct) {
                int col = ct * 16 + l15;
                s16x8 b = *(const s16x8*)(Bs + col * 512 + ((((ks << 2) | hi) ^ bxor) << 3));
                sacc[ct] = __builtin_amdgcn_mfma_f32_16x16x32_bf16(a, b, sacc[ct], 0, 0, 0);
            }
        }
    }
    __syncthreads();   // B reads complete; reuse Bs[0..17408) as t2 tile [128][136]

    {
        int rloc = wave * 16 + (hi << 2);
        #pragma unroll
        for (int ct = 0; ct < 8; ++ct) {
            int col = ct * 16 + l15;
            #pragma unroll
            for (int r = 0; r < 4; ++r)
                Bs[(rloc + r) * 136 + col] = f2bf(sacc[ct][r]);
        }
    }
    __syncthreads();

    // ---- conv phase: h = A0@W0 + A1@W1 + t2@W2 ----
    f32x4 acc[8];
    #pragma unroll
    for (int ct = 0; ct < 8; ++ct) acc[ct] = (f32x4){0.f, 0.f, 0.f, 0.f};
    const int arow = blockIdx.x * 128 + lrow;
    #pragma unroll
    for (int ks = 0; ks < 12; ++ks) {
        s16x8 a;
        if (ks < 4) {
            a = *(const s16x8*)(A0 + (size_t)arow * F + ks * 32 + hi * 8);
        } else if (ks < 8) {
            a = *(const s16x8*)(A1 + (size_t)arow * F + (ks - 4) * 32 + hi * 8);
        } else {
            a = *(const s16x8*)(Bs + lrow * 136 + (ks - 8) * 32 + hi * 8);
        }
        const unsigned short* wb = Wswz + ((size_t)ks * 512 + lane) * 8;
        #pragma unroll
        for (int ct = 0; ct < 8; ++ct) {
            s16x8 b = *(const s16x8*)(wb + (size_t)ct * 512);
            acc[ct] = __builtin_amdgcn_mfma_f32_16x16x32_bf16(a, b, acc[ct], 0, 0, 0);
        }
    }

    const int rloc = wave * 16 + (hi << 2);
    if (WRITE_H) {
        unsigned short* OutS = Bs + 40960;   // disjoint from t2 tile [0,17408)
        #pragma unroll
        for (int ct = 0; ct < 8; ++ct) {
            int col = ct * 16 + l15;
            float b = bias[col];
            float v0 = fmaxf(acc[ct][0] + b, 0.f);
            float v1 = fmaxf(acc[ct][1] + b, 0.f);
            float v2 = fmaxf(acc[ct][2] + b, 0.f);
            float v3 = fmaxf(acc[ct][3] + b, 0.f);
            uint2 w;
            w.x = pack16(v0, v1);
            w.y = pack16(v2, v3);
            *(uint2*)(Hc + (size_t)g * F * NG + (size_t)col * NG + rt * 128 + rloc) = w;
            OutS[(rloc + 0) * F + col] = f2bf(v0);
            OutS[(rloc + 1) * F + col] = f2bf(v1);
            OutS[(rloc + 2) * F + col] = f2bf(v2);
            OutS[(rloc + 3) * F + col] = f2bf(v3);
        }
        __syncthreads();
        uint4* o4 = (uint4*)(Hr + ((size_t)g * NG + rt * 128) * F);
        const uint4* s4 = (const uint4*)OutS;
        #pragma unroll
        for (int u = tid; u < 128 * F / 8; u += 512) o4[u] = s4[u];
    } else {
        __syncthreads();   // t2-tile reads done before aliasing with wmax
        float* wmax = (float*)Bs;
        #pragma unroll
        for (int ct = 0; ct < 8; ++ct) {
            int col = ct * 16 + l15;
            float b = bias[col];
            float m = fmaxf(fmaxf(acc[ct][0], acc[ct][1]), fmaxf(acc[ct][2], acc[ct][3]));
            m = fmaxf(m + b, 0.f);
            m = fmaxf(m, __shfl_xor(m, 16));
            m = fmaxf(m, __shfl_xor(m, 32));
            if (lane < 16) wmax[wave * F + col] = m;
        }
        __syncthreads();
        if (tid < F) {
            float m = wmax[tid];
            #pragma unroll
            for (int w = 1; w < 8; ++w) m = fmaxf(m, wmax[w * F + tid]);
            pooledp[((size_t)rt * 64 + g) * F + tid] = m;
        }
    }
}

// ---------------- output head: pooled = max over 4 partials; out = pooled @ Wout + bout ----

__global__ __launch_bounds__(64) void out_gemm_kernel(const float* __restrict__ pooledp,
                                                      const float* __restrict__ Wout,
                                                      const float* __restrict__ bout,
                                                      float* __restrict__ out) {
    __shared__ float p[F];
    int b = blockIdx.x, t = threadIdx.x;
    #pragma unroll
    for (int c = t; c < F; c += 64) {
        float m = pooledp[(size_t)b * F + c];
        m = fmaxf(m, pooledp[((size_t)64 + b) * F + c]);
        m = fmaxf(m, pooledp[((size_t)128 + b) * F + c]);
        m = fmaxf(m, pooledp[((size_t)192 + b) * F + c]);
        p[c] = m;
    }
    __syncthreads();
    float acc = bout[t];
    #pragma unroll 8
    for (int k = 0; k < F; ++k) acc += p[k] * Wout[k * 64 + t];
    out[(size_t)b * 64 + t] = acc;
}

// ---------------- launch ----------------

extern "C" void kernel_launch(void* const* d_in, const int* in_sizes, int n_in,
                              void* d_out, int out_size, void* d_ws, size_t ws_size,
                              hipStream_t stream) {
    const float* X     = (const float*)d_in[0];
    const int*   ei    = (const int*)d_in[2];
    const float* W1    = (const float*)d_in[3];
    const float* b1    = (const float*)d_in[4];
    const float* W2    = (const float*)d_in[5];
    const float* b2    = (const float*)d_in[6];
    const float* Wout  = (const float*)d_in[7];
    const float* bout  = (const float*)d_in[8];
    const float* alpha = (const float*)d_in[9];

    const int N = in_sizes[0] / F;   // 32768
    const int E = in_sizes[2] / 2;   // 524288
    const int Bg = N / NG;           // 64

    const int* srcv = ei;
    const int* dstv = ei + E;

    char* ws = (char*)d_ws;
    const size_t SBYTES = (size_t)Bg * NG * NG * 2;   // 33.55 MB
    const size_t PBYTES = (size_t)N * F * 2;          // 8.39 MB

    unsigned short* Sb = (unsigned short*)ws;
    unsigned short* P0 = (unsigned short*)(ws + SBYTES);               // Xr -> h1r
    unsigned short* P1 = (unsigned short*)(ws + SBYTES + PBYTES);      // Xc -> h1c
    unsigned short* P2 = (unsigned short*)(ws + SBYTES + 2 * PBYTES);  // t1r / u1r
    unsigned short* P3 = (unsigned short*)(ws + SBYTES + 3 * PBYTES);  // t1c / u1c
    char* tail = ws + SBYTES + 4 * PBYTES;
    unsigned short* Wswz1 = (unsigned short*)tail;
    unsigned short* Wswz2 = Wswz1 + (size_t)3 * F * F;
    float* pooledp = (float*)(Wswz2 + (size_t)3 * F * F);             // [4][64][128]
    // cnt aliases P2+P3 (exactly 16.78 MB); consumed by sgen before sapply writes P2/P3
    unsigned int* cnt32 = (unsigned int*)P2;

    // prep: cast X + shuffle weights + zero cnt (no in-graph memsets)
    prep_kernel<<<1920, 256, 0, stream>>>(X, P0, P1, W1, W2, Wswz1, Wswz2, (uint4*)cnt32);

    // dense S build
    cnt_scatter_kernel<<<(E + 255) / 256, 256, 0, stream>>>(srcv, dstv, cnt32, E);
    sgen_kernel<<<(Bg * NG * NG / 8) / 256, 256, 0, stream>>>((const unsigned char*)cnt32, Sb, alpha);

    // layer 1: t1 = S@X ; h1 = relu(X@W0 + t1@W1 + (S@t1)@W2 + b1)
    sapply_kernel<<<Bg * 4, 512, 0, stream>>>(Sb, P1, P2, P3);
    fused_conv_kernel<1><<<Bg * 4, 512, 0, stream>>>(Sb, P3, P0, P2, Wswz1, b1, P0, P1, nullptr);

    // layer 2: u1 = S@h1 ; pooledp = blockwise colmax(relu(h1@W0 + u1@W1 + (S@u1)@W2 + b2))
    sapply_kernel<<<Bg * 4, 512, 0, stream>>>(Sb, P1, P2, P3);
    fused_conv_kernel<0><<<Bg * 4, 512, 0, stream>>>(Sb, P3, P0, P2, Wswz2, b2, nullptr, nullptr, pooledp);

    // head
    out_gemm_kernel<<<Bg, 64, 0, stream>>>(pooledp, Wout, bout, (float*)d_out);
}

// Round 10
// 127.853 us; speedup vs baseline: 2.1458x; 1.0726x over previous
//
#include <hip/hip_runtime.h>
#include <hip/hip_bf16.h>

#define F 128
#define NG 512

typedef __attribute__((ext_vector_type(8))) short s16x8;
typedef __attribute__((ext_vector_type(4))) float f32x4;

__device__ inline float bf2f(unsigned short u) {
    unsigned int x = ((unsigned int)u) << 16;
    return __builtin_bit_cast(float, x);
}
__device__ inline unsigned short f2bf(float f) {
    __hip_bfloat16 h = __float2bfloat16(f);
    return __builtin_bit_cast(unsigned short, h);
}
__device__ inline unsigned int pack16(float x, float y) {
    return (unsigned int)f2bf(x) | ((unsigned int)f2bf(y) << 16);
}

// build one bf16 A-fragment of S on the fly from u8 counts:
// S[row][k] = alpha*cnt[row][k] + (row==k)*(1-alpha);  k = kbase..kbase+7
__device__ inline s16x8 sfrag(const unsigned char* __restrict__ crow, int kbase, int row,
                              float alpha, float diagv) {
    uint2 b8 = *(const uint2*)(crow + kbase);
    s16x8 a;
    #pragma unroll
    for (int j = 0; j < 8; ++j) {
        unsigned bj = ((j < 4) ? (b8.x >> (8 * j)) : (b8.y >> (8 * (j - 4)))) & 0xffu;
        float v = alpha * (float)bj + ((kbase + j) == row ? diagv : 0.f);
        a[j] = (short)f2bf(v);
    }
    return a;
}

// ---- prep: cast X (row+col major bf16) + shuffle weights + zero edge counters ----
// blocks [0,512): X cast; [512,896): weight shuffle; [896,1920): zero cnt (16.78 MB)

__global__ __launch_bounds__(256) void prep_kernel(const float* __restrict__ X,
                                                   unsigned short* __restrict__ Xr,
                                                   unsigned short* __restrict__ Xc,
                                                   const float* __restrict__ W1,
                                                   const float* __restrict__ W2,
                                                   unsigned short* __restrict__ o1,
                                                   unsigned short* __restrict__ o2,
                                                   uint4* __restrict__ cntz) {
    __shared__ unsigned short tile[64][F + 4];
    int tid = threadIdx.x;
    if (blockIdx.x < 512) {
        int g = blockIdx.x >> 3;
        int nt = blockIdx.x & 7;
        int node0 = nt * 64;
        const float* Xg = X + ((size_t)g * NG + node0) * F;
        unsigned short* Xrg = Xr + ((size_t)g * NG + node0) * F;
        #pragma unroll
        for (int u = tid; u < 64 * 32; u += 256) {
            int row = u >> 5, c4 = u & 31;
            float4 v = ((const float4*)(Xg + (size_t)row * F))[c4];
            unsigned short a0 = f2bf(v.x), a1 = f2bf(v.y), a2 = f2bf(v.z), a3 = f2bf(v.w);
            tile[row][c4 * 4 + 0] = a0;
            tile[row][c4 * 4 + 1] = a1;
            tile[row][c4 * 4 + 2] = a2;
            tile[row][c4 * 4 + 3] = a3;
            uint2 w;
            w.x = (unsigned int)a0 | ((unsigned int)a1 << 16);
            w.y = (unsigned int)a2 | ((unsigned int)a3 << 16);
            ((uint2*)(Xrg + (size_t)row * F))[c4] = w;
        }
        __syncthreads();
        unsigned short* Xcg = Xc + (size_t)g * F * NG;
        #pragma unroll
        for (int u = tid; u < F * 16; u += 256) {
            int f = u >> 4, nb = u & 15;
            int n0 = nb * 4;
            uint2 w;
            w.x = (unsigned int)tile[n0 + 0][f] | ((unsigned int)tile[n0 + 1][f] << 16);
            w.y = (unsigned int)tile[n0 + 2][f] | ((unsigned int)tile[n0 + 3][f] << 16);
            ((uint2*)(Xcg + (size_t)f * NG + node0))[nb] = w;
        }
    } else if (blockIdx.x < 896) {
        int t = (blockIdx.x - 512) * 256 + tid;   // [0, 98304)
        const float* W = (t < 49152) ? W1 : W2;
        unsigned short* o = (t < 49152) ? o1 : o2;
        int tt = (t < 49152) ? t : t - 49152;
        int j = tt & 7;
        int lane = (tt >> 3) & 63;
        int ct = (tt >> 9) & 7;
        int ks = tt >> 12;
        int k = ks * 32 + (lane >> 4) * 8 + j;
        int c = ct * 16 + (lane & 15);
        o[tt] = f2bf(W[(size_t)k * F + c]);
    } else {
        // zero 16.78 MB of cnt: 1024 blocks x 256 thr x 4 uint4
        size_t base = (size_t)(blockIdx.x - 896) * 1024;
        uint4 z = {0u, 0u, 0u, 0u};
        #pragma unroll
        for (int i = 0; i < 4; ++i) cntz[base + i * 256 + tid] = z;
    }
}

// ---------------- edge-count scatter (u8 packed in u32 atomics) ----------------

__global__ void cnt_scatter_kernel(const int* __restrict__ src, const int* __restrict__ dst,
                                   unsigned int* __restrict__ cnt32, int E) {
    int e = blockIdx.x * blockDim.x + threadIdx.x;
    if (e >= E) return;
    int s = src[e], d = dst[e];
    size_t idx = ((size_t)s << 9) | (unsigned)(d & (NG - 1));
    atomicAdd(&cnt32[idx >> 2], 1u << ((idx & 3) * 8));
}

// ---------------- S-apply with B staged in LDS: C[g] = S[g] @ B[g] (16x16x32) ----------------
// S synthesized on the fly from cnt (u8). B element [k][col] at
// Bs[col*512 + ((k>>3)^(col&7))*8 + (k&7)]  (chunk XOR swizzle).

__global__ __launch_bounds__(512) void sapply_kernel(
    const unsigned char* __restrict__ cnt, const float* __restrict__ alphap,
    const unsigned short* __restrict__ Bc,
    unsigned short* __restrict__ Cr, unsigned short* __restrict__ Cc) {
    __shared__ unsigned short Bs[65536];   // 128 KB
    const int g = blockIdx.x >> 2, rt = blockIdx.x & 3;
    const int tid = threadIdx.x, wave = tid >> 6, lane = tid & 63;
    const int l15 = lane & 15, hi = lane >> 4;
    const int lrow = wave * 16 + l15;
    const int row = rt * 128 + lrow;           // node index within graph
    const float alpha = *alphap;
    const float diagv = 1.0f - alpha;

    const unsigned short* Bcg = Bc + (size_t)g * F * NG;
    #pragma unroll
    for (int it = 0; it < 16; ++it) {
        int u = it * 512 + tid;
        int f = u >> 6, c = u & 63;
        *(uint4*)(Bs + f * 512 + ((c ^ (f & 7)) << 3)) =
            *(const uint4*)(Bcg + (size_t)f * NG + (c << 3));
    }
    __syncthreads();

    f32x4 acc[8];
    #pragma unroll
    for (int ct = 0; ct < 8; ++ct) acc[ct] = (f32x4){0.f, 0.f, 0.f, 0.f};

    const unsigned char* crow = cnt + ((size_t)g * NG + row) * NG;
    const int bxor = l15 & 7;
    #pragma unroll 4
    for (int ks = 0; ks < 16; ++ks) {
        s16x8 a = sfrag(crow, ks * 32 + hi * 8, row, alpha, diagv);
        #pragma unroll
        for (int ct = 0; ct < 8; ++ct) {
            int col = ct * 16 + l15;
            s16x8 b = *(const s16x8*)(Bs + col * 512 + ((((ks << 2) | hi) ^ bxor) << 3));
            acc[ct] = __builtin_amdgcn_mfma_f32_16x16x32_bf16(a, b, acc[ct], 0, 0, 0);
        }
    }
    __syncthreads();   // all waves done reading Bs; safe to reuse

    const int rloc = wave * 16 + (hi << 2);
    unsigned short* OutS = Bs + 40960;
    unsigned short* Ccg = Cc + (size_t)g * F * NG + rt * 128 + rloc;
    #pragma unroll
    for (int ct = 0; ct < 8; ++ct) {
        int col = ct * 16 + l15;
        uint2 w;
        w.x = pack16(acc[ct][0], acc[ct][1]);
        w.y = pack16(acc[ct][2], acc[ct][3]);
        *(uint2*)(Ccg + (size_t)col * NG) = w;
        #pragma unroll
        for (int r = 0; r < 4; ++r)
            OutS[(rloc + r) * F + col] = f2bf(acc[ct][r]);
    }
    __syncthreads();
    uint4* o4 = (uint4*)(Cr + ((size_t)g * NG + rt * 128) * F);
    const uint4* s4 = (const uint4*)OutS;
    #pragma unroll
    for (int u = tid; u < 128 * F / 8; u += 512) o4[u] = s4[u];
}

// ---------------- fused: t2 = S@Bc (LDS-staged B) -> t2 tile in LDS -> conv ----------------
// WRITE_H=1: h -> Hr (row) + Hc (col). WRITE_H=0: per-block col max -> pooledp[rt][g][F].

template <int WRITE_H>
__global__ __launch_bounds__(512) void fused_conv_kernel(
    const unsigned char* __restrict__ cnt, const float* __restrict__ alphap,
    const unsigned short* __restrict__ Bc,
    const unsigned short* __restrict__ A0, const unsigned short* __restrict__ A1,
    const unsigned short* __restrict__ Wswz, const float* __restrict__ bias,
    unsigned short* __restrict__ Hr, unsigned short* __restrict__ Hc,
    float* __restrict__ pooledp) {
    __shared__ unsigned short Bs[65536];   // 128 KB; B stage -> t2 tile [128][136] -> epilogue
    const int g = blockIdx.x >> 2, rt = blockIdx.x & 3;
    const int tid = threadIdx.x, wave = tid >> 6, lane = tid & 63;
    const int l15 = lane & 15, hi = lane >> 4;
    const int lrow = wave * 16 + l15;
    const int row = rt * 128 + lrow;
    const float alpha = *alphap;
    const float diagv = 1.0f - alpha;

    const unsigned short* Bcg = Bc + (size_t)g * F * NG;
    #pragma unroll
    for (int it = 0; it < 16; ++it) {
        int u = it * 512 + tid;
        int f = u >> 6, c = u & 63;
        *(uint4*)(Bs + f * 512 + ((c ^ (f & 7)) << 3)) =
            *(const uint4*)(Bcg + (size_t)f * NG + (c << 3));
    }
    __syncthreads();

    // ---- S-phase: t2 tile = S(rows) @ B ----
    f32x4 sacc[8];
    #pragma unroll
    for (int ct = 0; ct < 8; ++ct) sacc[ct] = (f32x4){0.f, 0.f, 0.f, 0.f};
    {
        const unsigned char* crow = cnt + ((size_t)g * NG + row) * NG;
        const int bxor = l15 & 7;
        #pragma unroll 4
        for (int ks = 0; ks < 16; ++ks) {
            s16x8 a = sfrag(crow, ks * 32 + hi * 8, row, alpha, diagv);
            #pragma unroll
            for (int ct = 0; ct < 8; ++ct) {
                int col = ct * 16 + l15;
                s16x8 b = *(const s16x8*)(Bs + col * 512 + ((((ks << 2) | hi) ^ bxor) << 3));
                sacc[ct] = __builtin_amdgcn_mfma_f32_16x16x32_bf16(a, b, sacc[ct], 0, 0, 0);
            }
        }
    }
    __syncthreads();   // B reads complete; reuse Bs[0..17408) as t2 tile [128][136]

    {
        int rloc = wave * 16 + (hi << 2);
        #pragma unroll
        for (int ct = 0; ct < 8; ++ct) {
            int col = ct * 16 + l15;
            #pragma unroll
            for (int r = 0; r < 4; ++r)
                Bs[(rloc + r) * 136 + col] = f2bf(sacc[ct][r]);
        }
    }
    __syncthreads();

    // ---- conv phase: h = A0@W0 + A1@W1 + t2@W2 ----
    f32x4 acc[8];
    #pragma unroll
    for (int ct = 0; ct < 8; ++ct) acc[ct] = (f32x4){0.f, 0.f, 0.f, 0.f};
    const int arow = blockIdx.x * 128 + lrow;
    #pragma unroll
    for (int ks = 0; ks < 12; ++ks) {
        s16x8 a;
        if (ks < 4) {
            a = *(const s16x8*)(A0 + (size_t)arow * F + ks * 32 + hi * 8);
        } else if (ks < 8) {
            a = *(const s16x8*)(A1 + (size_t)arow * F + (ks - 4) * 32 + hi * 8);
        } else {
            a = *(const s16x8*)(Bs + lrow * 136 + (ks - 8) * 32 + hi * 8);
        }
        const unsigned short* wb = Wswz + ((size_t)ks * 512 + lane) * 8;
        #pragma unroll
        for (int ct = 0; ct < 8; ++ct) {
            s16x8 b = *(const s16x8*)(wb + (size_t)ct * 512);
            acc[ct] = __builtin_amdgcn_mfma_f32_16x16x32_bf16(a, b, acc[ct], 0, 0, 0);
        }
    }

    const int rloc = wave * 16 + (hi << 2);
    if (WRITE_H) {
        unsigned short* OutS = Bs + 40960;   // disjoint from t2 tile [0,17408)
        #pragma unroll
        for (int ct = 0; ct < 8; ++ct) {
            int col = ct * 16 + l15;
            float b = bias[col];
            float v0 = fmaxf(acc[ct][0] + b, 0.f);
            float v1 = fmaxf(acc[ct][1] + b, 0.f);
            float v2 = fmaxf(acc[ct][2] + b, 0.f);
            float v3 = fmaxf(acc[ct][3] + b, 0.f);
            uint2 w;
            w.x = pack16(v0, v1);
            w.y = pack16(v2, v3);
            *(uint2*)(Hc + (size_t)g * F * NG + (size_t)col * NG + rt * 128 + rloc) = w;
            OutS[(rloc + 0) * F + col] = f2bf(v0);
            OutS[(rloc + 1) * F + col] = f2bf(v1);
            OutS[(rloc + 2) * F + col] = f2bf(v2);
            OutS[(rloc + 3) * F + col] = f2bf(v3);
        }
        __syncthreads();
        uint4* o4 = (uint4*)(Hr + ((size_t)g * NG + rt * 128) * F);
        const uint4* s4 = (const uint4*)OutS;
        #pragma unroll
        for (int u = tid; u < 128 * F / 8; u += 512) o4[u] = s4[u];
    } else {
        __syncthreads();   // t2-tile reads done before aliasing with wmax
        float* wmax = (float*)Bs;
        #pragma unroll
        for (int ct = 0; ct < 8; ++ct) {
            int col = ct * 16 + l15;
            float b = bias[col];
            float m = fmaxf(fmaxf(acc[ct][0], acc[ct][1]), fmaxf(acc[ct][2], acc[ct][3]));
            m = fmaxf(m + b, 0.f);
            m = fmaxf(m, __shfl_xor(m, 16));
            m = fmaxf(m, __shfl_xor(m, 32));
            if (lane < 16) wmax[wave * F + col] = m;
        }
        __syncthreads();
        if (tid < F) {
            float m = wmax[tid];
            #pragma unroll
            for (int w = 1; w < 8; ++w) m = fmaxf(m, wmax[w * F + tid]);
            pooledp[((size_t)rt * 64 + g) * F + tid] = m;
        }
    }
}

// ---------------- output head: pooled = max over 4 partials; out = pooled @ Wout + bout ----

__global__ __launch_bounds__(64) void out_gemm_kernel(const float* __restrict__ pooledp,
                                                      const float* __restrict__ Wout,
                                                      const float* __restrict__ bout,
                                                      float* __restrict__ out) {
    __shared__ float p[F];
    int b = blockIdx.x, t = threadIdx.x;
    #pragma unroll
    for (int c = t; c < F; c += 64) {
        float m = pooledp[(size_t)b * F + c];
        m = fmaxf(m, pooledp[((size_t)64 + b) * F + c]);
        m = fmaxf(m, pooledp[((size_t)128 + b) * F + c]);
        m = fmaxf(m, pooledp[((size_t)192 + b) * F + c]);
        p[c] = m;
    }
    __syncthreads();
    float acc = bout[t];
    #pragma unroll 8
    for (int k = 0; k < F; ++k) acc += p[k] * Wout[k * 64 + t];
    out[(size_t)b * 64 + t] = acc;
}

// ---------------- launch ----------------

extern "C" void kernel_launch(void* const* d_in, const int* in_sizes, int n_in,
                              void* d_out, int out_size, void* d_ws, size_t ws_size,
                              hipStream_t stream) {
    const float* X     = (const float*)d_in[0];
    const int*   ei    = (const int*)d_in[2];
    const float* W1    = (const float*)d_in[3];
    const float* b1    = (const float*)d_in[4];
    const float* W2    = (const float*)d_in[5];
    const float* b2    = (const float*)d_in[6];
    const float* Wout  = (const float*)d_in[7];
    const float* bout  = (const float*)d_in[8];
    const float* alpha = (const float*)d_in[9];

    const int N = in_sizes[0] / F;   // 32768
    const int E = in_sizes[2] / 2;   // 524288
    const int Bg = N / NG;           // 64

    const int* srcv = ei;
    const int* dstv = ei + E;

    char* ws = (char*)d_ws;
    const size_t CBYTES = (size_t)Bg * NG * NG;       // 16.78 MB (u8 counts, lives all run)
    const size_t PBYTES = (size_t)N * F * 2;          // 8.39 MB

    unsigned char* cnt8 = (unsigned char*)ws;
    unsigned short* P0 = (unsigned short*)(ws + CBYTES);               // Xr -> h1r
    unsigned short* P1 = (unsigned short*)(ws + CBYTES + PBYTES);      // Xc -> h1c
    unsigned short* P2 = (unsigned short*)(ws + CBYTES + 2 * PBYTES);  // t1r / u1r
    unsigned short* P3 = (unsigned short*)(ws + CBYTES + 3 * PBYTES);  // t1c / u1c
    char* tail = ws + CBYTES + 4 * PBYTES;
    unsigned short* Wswz1 = (unsigned short*)tail;
    unsigned short* Wswz2 = Wswz1 + (size_t)3 * F * F;
    float* pooledp = (float*)(Wswz2 + (size_t)3 * F * F);             // [4][64][128]

    // prep: cast X + shuffle weights + zero cnt (no in-graph memsets)
    prep_kernel<<<1920, 256, 0, stream>>>(X, P0, P1, W1, W2, Wswz1, Wswz2, (uint4*)cnt8);

    // edge-count scatter
    cnt_scatter_kernel<<<(E + 255) / 256, 256, 0, stream>>>(srcv, dstv, (unsigned int*)cnt8, E);

    // layer 1: t1 = S@X ; h1 = relu(X@W0 + t1@W1 + (S@t1)@W2 + b1)
    sapply_kernel<<<Bg * 4, 512, 0, stream>>>(cnt8, alpha, P1, P2, P3);
    fused_conv_kernel<1><<<Bg * 4, 512, 0, stream>>>(cnt8, alpha, P3, P0, P2, Wswz1, b1, P0, P1, nullptr);

    // layer 2: u1 = S@h1 ; pooledp = blockwise colmax(relu(h1@W0 + u1@W1 + (S@u1)@W2 + b2))
    sapply_kernel<<<Bg * 4, 512, 0, stream>>>(cnt8, alpha, P1, P2, P3);
    fused_conv_kernel<0><<<Bg * 4, 512, 0, stream>>>(cnt8, alpha, P3, P0, P2, Wswz2, b2, nullptr, nullptr, pooledp);

    // head
    out_gemm_kernel<<<Bg, 64, 0, stream>>>(pooledp, Wout, bout, (float*)d_out);
}

// Round 11
// 123.426 us; speedup vs baseline: 2.2228x; 1.0359x over previous
//
#include <hip/hip_runtime.h>
#include <hip/hip_bf16.h>

#define F 128
#define NG 512

typedef __attribute__((ext_vector_type(8))) short s16x8;
typedef __attribute__((ext_vector_type(4))) float f32x4;

__device__ inline float bf2f(unsigned short u) {
    unsigned int x = ((unsigned int)u) << 16;
    return __builtin_bit_cast(float, x);
}
__device__ inline unsigned short f2bf(float f) {
    __hip_bfloat16 h = __float2bfloat16(f);
    return __builtin_bit_cast(unsigned short, h);
}
__device__ inline unsigned int pack16(float x, float y) {
    return (unsigned int)f2bf(x) | ((unsigned int)f2bf(y) << 16);
}

// build one bf16 A-fragment of S from one u32 of 8 nibble-counts:
// S[row][kbase+j] = alpha*cnt + (row==kbase+j)*(1-alpha)
__device__ inline s16x8 sfrag4(unsigned w, int kbase, int row, float alpha, float diagv) {
    s16x8 a;
    #pragma unroll
    for (int j = 0; j < 8; ++j) {
        float v = alpha * (float)((w >> (4 * j)) & 0xFu);
        if (kbase + j == row) v += diagv;
        a[j] = (short)f2bf(v);
    }
    return a;
}

// ---- prep: cast X (row+col major bf16) + shuffle weights + zero nibble counters ----
// blocks [0,512): X cast; [512,896): weight shuffle; [896,1408): zero cnt (8.39 MB)

__global__ __launch_bounds__(256) void prep_kernel(const float* __restrict__ X,
                                                   unsigned short* __restrict__ Xr,
                                                   unsigned short* __restrict__ Xc,
                                                   const float* __restrict__ W1,
                                                   const float* __restrict__ W2,
                                                   unsigned short* __restrict__ o1,
                                                   unsigned short* __restrict__ o2,
                                                   uint4* __restrict__ cntz) {
    __shared__ unsigned short tile[64][F + 4];
    int tid = threadIdx.x;
    if (blockIdx.x < 512) {
        int g = blockIdx.x >> 3;
        int nt = blockIdx.x & 7;
        int node0 = nt * 64;
        const float* Xg = X + ((size_t)g * NG + node0) * F;
        unsigned short* Xrg = Xr + ((size_t)g * NG + node0) * F;
        #pragma unroll
        for (int u = tid; u < 64 * 32; u += 256) {
            int row = u >> 5, c4 = u & 31;
            float4 v = ((const float4*)(Xg + (size_t)row * F))[c4];
            unsigned short a0 = f2bf(v.x), a1 = f2bf(v.y), a2 = f2bf(v.z), a3 = f2bf(v.w);
            tile[row][c4 * 4 + 0] = a0;
            tile[row][c4 * 4 + 1] = a1;
            tile[row][c4 * 4 + 2] = a2;
            tile[row][c4 * 4 + 3] = a3;
            uint2 w;
            w.x = (unsigned int)a0 | ((unsigned int)a1 << 16);
            w.y = (unsigned int)a2 | ((unsigned int)a3 << 16);
            ((uint2*)(Xrg + (size_t)row * F))[c4] = w;
        }
        __syncthreads();
        unsigned short* Xcg = Xc + (size_t)g * F * NG;
        #pragma unroll
        for (int u = tid; u < F * 16; u += 256) {
            int f = u >> 4, nb = u & 15;
            int n0 = nb * 4;
            uint2 w;
            w.x = (unsigned int)tile[n0 + 0][f] | ((unsigned int)tile[n0 + 1][f] << 16);
            w.y = (unsigned int)tile[n0 + 2][f] | ((unsigned int)tile[n0 + 3][f] << 16);
            ((uint2*)(Xcg + (size_t)f * NG + node0))[nb] = w;
        }
    } else if (blockIdx.x < 896) {
        int t = (blockIdx.x - 512) * 256 + tid;   // [0, 98304)
        const float* W = (t < 49152) ? W1 : W2;
        unsigned short* o = (t < 49152) ? o1 : o2;
        int tt = (t < 49152) ? t : t - 49152;
        int j = tt & 7;
        int lane = (tt >> 3) & 63;
        int ct = (tt >> 9) & 7;
        int ks = tt >> 12;
        int k = ks * 32 + (lane >> 4) * 8 + j;
        int c = ct * 16 + (lane & 15);
        o[tt] = f2bf(W[(size_t)k * F + c]);
    } else {
        // zero 8.39 MB of nibble counts: 512 blocks x 256 thr x 4 uint4
        size_t base = (size_t)(blockIdx.x - 896) * 1024;
        uint4 z = {0u, 0u, 0u, 0u};
        #pragma unroll
        for (int i = 0; i < 4; ++i) cntz[base + i * 256 + tid] = z;
    }
}

// ---------------- edge-count scatter (u4 nibbles packed in u32 atomics) ----------------

__global__ void cnt_scatter_kernel(const int* __restrict__ src, const int* __restrict__ dst,
                                   unsigned int* __restrict__ cnt4, int E) {
    int e = blockIdx.x * blockDim.x + threadIdx.x;
    if (e >= E) return;
    int s = src[e], d = dst[e];
    size_t idx = ((size_t)s << 9) | (unsigned)(d & (NG - 1));
    atomicAdd(&cnt4[idx >> 3], 1u << ((idx & 7) * 4));
}

// ---------------- S-apply with B staged in LDS: Cc[g] = S[g] @ B[g] (16x16x32) ----------------
// S synthesized on the fly from nibble counts. B element [k][col] at
// Bs[col*512 + ((k>>3)^(col&7))*8 + (k&7)]  (chunk XOR swizzle). Output: col-major only.

__global__ __launch_bounds__(512) void sapply_kernel(
    const unsigned int* __restrict__ cnt4, const float* __restrict__ alphap,
    const unsigned short* __restrict__ Bc, unsigned short* __restrict__ Cc) {
    __shared__ unsigned short Bs[65536];   // 128 KB
    const int g = blockIdx.x >> 2, rt = blockIdx.x & 3;
    const int tid = threadIdx.x, wave = tid >> 6, lane = tid & 63;
    const int l15 = lane & 15, hi = lane >> 4;
    const int lrow = wave * 16 + l15;
    const int row = rt * 128 + lrow;           // node index within graph
    const float alpha = *alphap;
    const float diagv = 1.0f - alpha;

    const unsigned short* Bcg = Bc + (size_t)g * F * NG;
    #pragma unroll
    for (int it = 0; it < 16; ++it) {
        int u = it * 512 + tid;
        int f = u >> 6, c = u & 63;
        *(uint4*)(Bs + f * 512 + ((c ^ (f & 7)) << 3)) =
            *(const uint4*)(Bcg + (size_t)f * NG + (c << 3));
    }
    __syncthreads();

    f32x4 acc[8];
    #pragma unroll
    for (int ct = 0; ct < 8; ++ct) acc[ct] = (f32x4){0.f, 0.f, 0.f, 0.f};

    const unsigned int* crow = cnt4 + ((size_t)g * NG + row) * 64;   // 64 words per row
    const int bxor = l15 & 7;
    #pragma unroll 4
    for (int ks = 0; ks < 16; ++ks) {
        s16x8 a = sfrag4(crow[ks * 4 + hi], ks * 32 + hi * 8, row, alpha, diagv);
        #pragma unroll
        for (int ct = 0; ct < 8; ++ct) {
            int col = ct * 16 + l15;
            s16x8 b = *(const s16x8*)(Bs + col * 512 + ((((ks << 2) | hi) ^ bxor) << 3));
            acc[ct] = __builtin_amdgcn_mfma_f32_16x16x32_bf16(a, b, acc[ct], 0, 0, 0);
        }
    }

    // epilogue: col-major direct store only
    const int rloc = wave * 16 + (hi << 2);
    unsigned short* Ccg = Cc + (size_t)g * F * NG + rt * 128 + rloc;
    #pragma unroll
    for (int ct = 0; ct < 8; ++ct) {
        int col = ct * 16 + l15;
        uint2 w;
        w.x = pack16(acc[ct][0], acc[ct][1]);
        w.y = pack16(acc[ct][2], acc[ct][3]);
        *(uint2*)(Ccg + (size_t)col * NG) = w;
    }
}

// ---------------- fused: t2 = S@Bc (LDS-staged B) -> t2 tile in LDS -> conv ----------------
// conv A1 (t1) fragments are captured from the staged Bs into registers before the
// t2 tile overwrites it. WRITE_H=1: h -> Hr+Hc. WRITE_H=0: col max -> pooledp.

template <int WRITE_H>
__global__ __launch_bounds__(512) void fused_conv_kernel(
    const unsigned int* __restrict__ cnt4, const float* __restrict__ alphap,
    const unsigned short* __restrict__ Bc, const unsigned short* __restrict__ A0,
    const unsigned short* __restrict__ Wswz, const float* __restrict__ bias,
    unsigned short* __restrict__ Hr, unsigned short* __restrict__ Hc,
    float* __restrict__ pooledp) {
    __shared__ unsigned short Bs[65536];   // 128 KB; B stage -> t2 tile [128][136] -> epilogue
    const int g = blockIdx.x >> 2, rt = blockIdx.x & 3;
    const int tid = threadIdx.x, wave = tid >> 6, lane = tid & 63;
    const int l15 = lane & 15, hi = lane >> 4;
    const int lrow = wave * 16 + l15;
    const int row = rt * 128 + lrow;
    const float alpha = *alphap;
    const float diagv = 1.0f - alpha;

    const unsigned short* Bcg = Bc + (size_t)g * F * NG;
    #pragma unroll
    for (int it = 0; it < 16; ++it) {
        int u = it * 512 + tid;
        int f = u >> 6, c = u & 63;
        *(uint4*)(Bs + f * 512 + ((c ^ (f & 7)) << 3)) =
            *(const uint4*)(Bcg + (size_t)f * NG + (c << 3));
    }
    __syncthreads();

    // ---- S-phase: t2 tile = S(rows) @ B ----
    f32x4 sacc[8];
    #pragma unroll
    for (int ct = 0; ct < 8; ++ct) sacc[ct] = (f32x4){0.f, 0.f, 0.f, 0.f};
    {
        const unsigned int* crow = cnt4 + ((size_t)g * NG + row) * 64;
        const int bxor = l15 & 7;
        #pragma unroll 4
        for (int ks = 0; ks < 16; ++ks) {
            s16x8 a = sfrag4(crow[ks * 4 + hi], ks * 32 + hi * 8, row, alpha, diagv);
            #pragma unroll
            for (int ct = 0; ct < 8; ++ct) {
                int col = ct * 16 + l15;
                s16x8 b = *(const s16x8*)(Bs + col * 512 + ((((ks << 2) | hi) ^ bxor) << 3));
                sacc[ct] = __builtin_amdgcn_mfma_f32_16x16x32_bf16(a, b, sacc[ct], 0, 0, 0);
            }
        }
    }

    // ---- capture conv A1 (t1) fragments from Bs before it's overwritten ----
    // t1[row][f0+j] = Bs[(f0+j)*512 + ((row>>3)^j)*8 + (row&7)]   (f0 multiple of 8)
    s16x8 a1f[4];
    #pragma unroll
    for (int kk = 0; kk < 4; ++kk) {
        int f0 = kk * 32 + hi * 8;
        s16x8 t;
        #pragma unroll
        for (int j = 0; j < 8; ++j)
            t[j] = (short)Bs[(f0 + j) * 512 + (((lrow + rt * 128) >> 3 ^ j) << 3) + (row & 7)];
        a1f[kk] = t;
    }
    __syncthreads();   // B reads + captures complete; reuse Bs[0..17408) as t2 tile [128][136]

    {
        int rloc = wave * 16 + (hi << 2);
        #pragma unroll
        for (int ct = 0; ct < 8; ++ct) {
            int col = ct * 16 + l15;
            #pragma unroll
            for (int r = 0; r < 4; ++r)
                Bs[(rloc + r) * 136 + col] = f2bf(sacc[ct][r]);
        }
    }
    __syncthreads();

    // ---- conv phase: h = A0@W0 + t1@W1 + t2@W2 ----
    f32x4 acc[8];
    #pragma unroll
    for (int ct = 0; ct < 8; ++ct) acc[ct] = (f32x4){0.f, 0.f, 0.f, 0.f};
    const int arow = blockIdx.x * 128 + lrow;
    #pragma unroll
    for (int ks = 0; ks < 12; ++ks) {
        s16x8 a;
        if (ks < 4) {
            a = *(const s16x8*)(A0 + (size_t)arow * F + ks * 32 + hi * 8);
        } else if (ks < 8) {
            a = a1f[ks - 4];
        } else {
            a = *(const s16x8*)(Bs + lrow * 136 + (ks - 8) * 32 + hi * 8);
        }
        const unsigned short* wb = Wswz + ((size_t)ks * 512 + lane) * 8;
        #pragma unroll
        for (int ct = 0; ct < 8; ++ct) {
            s16x8 b = *(const s16x8*)(wb + (size_t)ct * 512);
            acc[ct] = __builtin_amdgcn_mfma_f32_16x16x32_bf16(a, b, acc[ct], 0, 0, 0);
        }
    }

    const int rloc = wave * 16 + (hi << 2);
    if (WRITE_H) {
        unsigned short* OutS = Bs + 40960;   // disjoint from t2 tile [0,17408)
        #pragma unroll
        for (int ct = 0; ct < 8; ++ct) {
            int col = ct * 16 + l15;
            float b = bias[col];
            float v0 = fmaxf(acc[ct][0] + b, 0.f);
            float v1 = fmaxf(acc[ct][1] + b, 0.f);
            float v2 = fmaxf(acc[ct][2] + b, 0.f);
            float v3 = fmaxf(acc[ct][3] + b, 0.f);
            uint2 w;
            w.x = pack16(v0, v1);
            w.y = pack16(v2, v3);
            *(uint2*)(Hc + (size_t)g * F * NG + (size_t)col * NG + rt * 128 + rloc) = w;
            OutS[(rloc + 0) * F + col] = f2bf(v0);
            OutS[(rloc + 1) * F + col] = f2bf(v1);
            OutS[(rloc + 2) * F + col] = f2bf(v2);
            OutS[(rloc + 3) * F + col] = f2bf(v3);
        }
        __syncthreads();
        uint4* o4 = (uint4*)(Hr + ((size_t)g * NG + rt * 128) * F);
        const uint4* s4 = (const uint4*)OutS;
        #pragma unroll
        for (int u = tid; u < 128 * F / 8; u += 512) o4[u] = s4[u];
    } else {
        __syncthreads();   // t2-tile reads done before aliasing with wmax
        float* wmax = (float*)Bs;
        #pragma unroll
        for (int ct = 0; ct < 8; ++ct) {
            int col = ct * 16 + l15;
            float b = bias[col];
            float m = fmaxf(fmaxf(acc[ct][0], acc[ct][1]), fmaxf(acc[ct][2], acc[ct][3]));
            m = fmaxf(m + b, 0.f);
            m = fmaxf(m, __shfl_xor(m, 16));
            m = fmaxf(m, __shfl_xor(m, 32));
            if (lane < 16) wmax[wave * F + col] = m;
        }
        __syncthreads();
        if (tid < F) {
            float m = wmax[tid];
            #pragma unroll
            for (int w = 1; w < 8; ++w) m = fmaxf(m, wmax[w * F + tid]);
            pooledp[((size_t)rt * 64 + g) * F + tid] = m;
        }
    }
}

// ---------------- output head: pooled = max over 4 partials; out = pooled @ Wout + bout ----

__global__ __launch_bounds__(64) void out_gemm_kernel(const float* __restrict__ pooledp,
                                                      const float* __restrict__ Wout,
                                                      const float* __restrict__ bout,
                                                      float* __restrict__ out) {
    __shared__ float p[F];
    int b = blockIdx.x, t = threadIdx.x;
    #pragma unroll
    for (int c = t; c < F; c += 64) {
        float m = pooledp[(size_t)b * F + c];
        m = fmaxf(m, pooledp[((size_t)64 + b) * F + c]);
        m = fmaxf(m, pooledp[((size_t)128 + b) * F + c]);
        m = fmaxf(m, pooledp[((size_t)192 + b) * F + c]);
        p[c] = m;
    }
    __syncthreads();
    float acc = bout[t];
    #pragma unroll 8
    for (int k = 0; k < F; ++k) acc += p[k] * Wout[k * 64 + t];
    out[(size_t)b * 64 + t] = acc;
}

// ---------------- launch ----------------

extern "C" void kernel_launch(void* const* d_in, const int* in_sizes, int n_in,
                              void* d_out, int out_size, void* d_ws, size_t ws_size,
                              hipStream_t stream) {
    const float* X     = (const float*)d_in[0];
    const int*   ei    = (const int*)d_in[2];
    const float* W1    = (const float*)d_in[3];
    const float* b1    = (const float*)d_in[4];
    const float* W2    = (const float*)d_in[5];
    const float* b2    = (const float*)d_in[6];
    const float* Wout  = (const float*)d_in[7];
    const float* bout  = (const float*)d_in[8];
    const float* alpha = (const float*)d_in[9];

    const int N = in_sizes[0] / F;   // 32768
    const int E = in_sizes[2] / 2;   // 524288
    const int Bg = N / NG;           // 64

    const int* srcv = ei;
    const int* dstv = ei + E;

    char* ws = (char*)d_ws;
    const size_t CBYTES = (size_t)Bg * NG * NG / 2;   // 8.39 MB (u4 counts, lives all run)
    const size_t PBYTES = (size_t)N * F * 2;          // 8.39 MB

    unsigned int* cnt4 = (unsigned int*)ws;
    unsigned short* P0 = (unsigned short*)(ws + CBYTES);               // Xr -> h1r
    unsigned short* P1 = (unsigned short*)(ws + CBYTES + PBYTES);      // Xc -> h1c
    unsigned short* P3 = (unsigned short*)(ws + CBYTES + 2 * PBYTES);  // t1c / u1c
    char* tail = ws + CBYTES + 3 * PBYTES;
    unsigned short* Wswz1 = (unsigned short*)tail;
    unsigned short* Wswz2 = Wswz1 + (size_t)3 * F * F;
    float* pooledp = (float*)(Wswz2 + (size_t)3 * F * F);             // [4][64][128]

    // prep: cast X + shuffle weights + zero cnt (no in-graph memsets)
    prep_kernel<<<1408, 256, 0, stream>>>(X, P0, P1, W1, W2, Wswz1, Wswz2, (uint4*)cnt4);

    // edge-count scatter (nibbles)
    cnt_scatter_kernel<<<(E + 255) / 256, 256, 0, stream>>>(srcv, dstv, cnt4, E);

    // layer 1: t1c = S@X ; h1 = relu(X@W0 + t1@W1 + (S@t1)@W2 + b1)
    sapply_kernel<<<Bg * 4, 512, 0, stream>>>(cnt4, alpha, P1, P3);
    fused_conv_kernel<1><<<Bg * 4, 512, 0, stream>>>(cnt4, alpha, P3, P0, Wswz1, b1, P0, P1, nullptr);

    // layer 2: u1c = S@h1 ; pooledp = blockwise colmax(relu(h1@W0 + u1@W1 + (S@u1)@W2 + b2))
    sapply_kernel<<<Bg * 4, 512, 0, stream>>>(cnt4, alpha, P1, P3);
    fused_conv_kernel<0><<<Bg * 4, 512, 0, stream>>>(cnt4, alpha, P3, P0, Wswz2, b2, nullptr, nullptr, pooledp);

    // head
    out_gemm_kernel<<<Bg, 64, 0, stream>>>(pooledp, Wout, bout, (float*)d_out);
}

// Round 12
// 110.601 us; speedup vs baseline: 2.4805x; 1.1160x over previous
//
#include <hip/hip_runtime.h>
#include <hip/hip_bf16.h>

#define F 128
#define NG 512

typedef __attribute__((ext_vector_type(8))) short s16x8;
typedef __attribute__((ext_vector_type(4))) float f32x4;

__device__ inline float bf2f(unsigned short u) {
    unsigned int x = ((unsigned int)u) << 16;
    return __builtin_bit_cast(float, x);
}
__device__ inline unsigned short f2bf(float f) {
    __hip_bfloat16 h = __float2bfloat16(f);
    return __builtin_bit_cast(unsigned short, h);
}
__device__ inline unsigned int pack16(float x, float y) {
    return (unsigned int)f2bf(x) | ((unsigned int)f2bf(y) << 16);
}

// async 16B global->LDS DMA: dest = lds_base + lane*16 (wave-uniform base)
typedef const __attribute__((address_space(1))) unsigned int guint;
typedef __attribute__((address_space(3))) unsigned int luint;
__device__ inline void stage16(const void* g, void* l) {
    __builtin_amdgcn_global_load_lds((guint*)g, (luint*)l, 16, 0, 0);
}

// build one bf16 A-fragment of S from one u32 of 8 nibble-counts:
// S[row][kbase+j] = alpha*cnt + (row==kbase+j)*(1-alpha)
__device__ inline s16x8 sfrag4(unsigned w, int kbase, int row, float alpha, float diagv) {
    s16x8 a;
    #pragma unroll
    for (int j = 0; j < 8; ++j) {
        float v = alpha * (float)((w >> (4 * j)) & 0xFu);
        if (kbase + j == row) v += diagv;
        a[j] = (short)f2bf(v);
    }
    return a;
}

// ---- prep: cast X (row+col major bf16) + shuffle weights + zero nibble counters ----
// blocks [0,512): X cast; [512,896): weight shuffle; [896,1408): zero cnt (8.39 MB)

__global__ __launch_bounds__(256) void prep_kernel(const float* __restrict__ X,
                                                   unsigned short* __restrict__ Xr,
                                                   unsigned short* __restrict__ Xc,
                                                   const float* __restrict__ W1,
                                                   const float* __restrict__ W2,
                                                   unsigned short* __restrict__ o1,
                                                   unsigned short* __restrict__ o2,
                                                   uint4* __restrict__ cntz) {
    __shared__ unsigned short tile[64][F + 4];
    int tid = threadIdx.x;
    if (blockIdx.x < 512) {
        int g = blockIdx.x >> 3;
        int nt = blockIdx.x & 7;
        int node0 = nt * 64;
        const float* Xg = X + ((size_t)g * NG + node0) * F;
        unsigned short* Xrg = Xr + ((size_t)g * NG + node0) * F;
        #pragma unroll
        for (int u = tid; u < 64 * 32; u += 256) {
            int row = u >> 5, c4 = u & 31;
            float4 v = ((const float4*)(Xg + (size_t)row * F))[c4];
            unsigned short a0 = f2bf(v.x), a1 = f2bf(v.y), a2 = f2bf(v.z), a3 = f2bf(v.w);
            tile[row][c4 * 4 + 0] = a0;
            tile[row][c4 * 4 + 1] = a1;
            tile[row][c4 * 4 + 2] = a2;
            tile[row][c4 * 4 + 3] = a3;
            uint2 w;
            w.x = (unsigned int)a0 | ((unsigned int)a1 << 16);
            w.y = (unsigned int)a2 | ((unsigned int)a3 << 16);
            ((uint2*)(Xrg + (size_t)row * F))[c4] = w;
        }
        __syncthreads();
        unsigned short* Xcg = Xc + (size_t)g * F * NG;
        #pragma unroll
        for (int u = tid; u < F * 16; u += 256) {
            int f = u >> 4, nb = u & 15;
            int n0 = nb * 4;
            uint2 w;
            w.x = (unsigned int)tile[n0 + 0][f] | ((unsigned int)tile[n0 + 1][f] << 16);
            w.y = (unsigned int)tile[n0 + 2][f] | ((unsigned int)tile[n0 + 3][f] << 16);
            ((uint2*)(Xcg + (size_t)f * NG + node0))[nb] = w;
        }
    } else if (blockIdx.x < 896) {
        int t = (blockIdx.x - 512) * 256 + tid;   // [0, 98304)
        const float* W = (t < 49152) ? W1 : W2;
        unsigned short* o = (t < 49152) ? o1 : o2;
        int tt = (t < 49152) ? t : t - 49152;
        int j = tt & 7;
        int lane = (tt >> 3) & 63;
        int ct = (tt >> 9) & 7;
        int ks = tt >> 12;
        int k = ks * 32 + (lane >> 4) * 8 + j;
        int c = ct * 16 + (lane & 15);
        o[tt] = f2bf(W[(size_t)k * F + c]);
    } else {
        // zero 8.39 MB of nibble counts: 512 blocks x 256 thr x 4 uint4
        size_t base = (size_t)(blockIdx.x - 896) * 1024;
        uint4 z = {0u, 0u, 0u, 0u};
        #pragma unroll
        for (int i = 0; i < 4; ++i) cntz[base + i * 256 + tid] = z;
    }
}

// ---------------- edge-count scatter (u4 nibbles packed in u32 atomics) ----------------

__global__ void cnt_scatter_kernel(const int* __restrict__ src, const int* __restrict__ dst,
                                   unsigned int* __restrict__ cnt4, int E) {
    int e = blockIdx.x * blockDim.x + threadIdx.x;
    if (e >= E) return;
    int s = src[e], d = dst[e];
    size_t idx = ((size_t)s << 9) | (unsigned)(d & (NG - 1));
    atomicAdd(&cnt4[idx >> 3], 1u << ((idx & 7) * 4));
}

// ---------------- S-apply with B staged in LDS: Cc[g] = S[g] @ B[g] (16x16x32) ----------------
// S synthesized on the fly from nibble counts. Staging: async global_load_lds with
// pre-swizzled global source, linear LDS dest. Element [k][col] readable at
// Bs[col*512 + ((k>>3)^(col&7))*8 + (k&7)]. Output: col-major only.
// XCD-chunked block swizzle: 4 sibling blocks of a graph share one XCD's L2.

__global__ __launch_bounds__(512) void sapply_kernel(
    const unsigned int* __restrict__ cnt4, const float* __restrict__ alphap,
    const unsigned short* __restrict__ Bc, unsigned short* __restrict__ Cc) {
    __shared__ unsigned short Bs[65536];   // 128 KB
    const int p = blockIdx.x;
    const int id = ((p & 7) << 5) | (p >> 3);
    const int g = id >> 2, rt = id & 3;
    const int tid = threadIdx.x, wave = tid >> 6, lane = tid & 63;
    const int l15 = lane & 15, hi = lane >> 4;
    const int lrow = wave * 16 + l15;
    const int row = rt * 128 + lrow;           // node index within graph
    const float alpha = *alphap;
    const float diagv = 1.0f - alpha;

    const unsigned short* Bcg = Bc + (size_t)g * F * NG;
    #pragma unroll
    for (int it = 0; it < 16; ++it) {
        int f = it * 8 + wave;                     // wave-uniform row (feature)
        stage16(Bcg + (size_t)f * NG + ((lane ^ (f & 7)) << 3), Bs + f * 512);
    }
    __syncthreads();

    f32x4 acc[8];
    #pragma unroll
    for (int ct = 0; ct < 8; ++ct) acc[ct] = (f32x4){0.f, 0.f, 0.f, 0.f};

    const unsigned int* crow = cnt4 + ((size_t)g * NG + row) * 64;   // 64 words per row
    const int bxor = l15 & 7;
    #pragma unroll 4
    for (int ks = 0; ks < 16; ++ks) {
        s16x8 a = sfrag4(crow[ks * 4 + hi], ks * 32 + hi * 8, row, alpha, diagv);
        #pragma unroll
        for (int ct = 0; ct < 8; ++ct) {
            int col = ct * 16 + l15;
            s16x8 b = *(const s16x8*)(Bs + col * 512 + ((((ks << 2) | hi) ^ bxor) << 3));
            acc[ct] = __builtin_amdgcn_mfma_f32_16x16x32_bf16(a, b, acc[ct], 0, 0, 0);
        }
    }

    // epilogue: col-major direct store only
    const int rloc = wave * 16 + (hi << 2);
    unsigned short* Ccg = Cc + (size_t)g * F * NG + rt * 128 + rloc;
    #pragma unroll
    for (int ct = 0; ct < 8; ++ct) {
        int col = ct * 16 + l15;
        uint2 w;
        w.x = pack16(acc[ct][0], acc[ct][1]);
        w.y = pack16(acc[ct][2], acc[ct][3]);
        *(uint2*)(Ccg + (size_t)col * NG) = w;
    }
}

// ---------------- fused: t2 = S@Bc (LDS-staged B) -> t2 tile in LDS -> conv ----------------
// conv A1 (t1) fragments are captured from the staged Bs into registers before the
// t2 tile overwrites it. WRITE_H=1: h -> Hr+Hc. WRITE_H=0: col max -> pooledp.

template <int WRITE_H>
__global__ __launch_bounds__(512) void fused_conv_kernel(
    const unsigned int* __restrict__ cnt4, const float* __restrict__ alphap,
    const unsigned short* __restrict__ Bc, const unsigned short* __restrict__ A0,
    const unsigned short* __restrict__ Wswz, const float* __restrict__ bias,
    unsigned short* __restrict__ Hr, unsigned short* __restrict__ Hc,
    float* __restrict__ pooledp) {
    __shared__ unsigned short Bs[65536];   // 128 KB; B stage -> t2 tile [128][136] -> epilogue
    const int p = blockIdx.x;
    const int id = ((p & 7) << 5) | (p >> 3);
    const int g = id >> 2, rt = id & 3;
    const int tid = threadIdx.x, wave = tid >> 6, lane = tid & 63;
    const int l15 = lane & 15, hi = lane >> 4;
    const int lrow = wave * 16 + l15;
    const int row = rt * 128 + lrow;
    const float alpha = *alphap;
    const float diagv = 1.0f - alpha;

    const unsigned short* Bcg = Bc + (size_t)g * F * NG;
    #pragma unroll
    for (int it = 0; it < 16; ++it) {
        int f = it * 8 + wave;
        stage16(Bcg + (size_t)f * NG + ((lane ^ (f & 7)) << 3), Bs + f * 512);
    }
    __syncthreads();

    // ---- S-phase: t2 tile = S(rows) @ B ----
    f32x4 sacc[8];
    #pragma unroll
    for (int ct = 0; ct < 8; ++ct) sacc[ct] = (f32x4){0.f, 0.f, 0.f, 0.f};
    {
        const unsigned int* crow = cnt4 + ((size_t)g * NG + row) * 64;
        const int bxor = l15 & 7;
        #pragma unroll 4
        for (int ks = 0; ks < 16; ++ks) {
            s16x8 a = sfrag4(crow[ks * 4 + hi], ks * 32 + hi * 8, row, alpha, diagv);
            #pragma unroll
            for (int ct = 0; ct < 8; ++ct) {
                int col = ct * 16 + l15;
                s16x8 b = *(const s16x8*)(Bs + col * 512 + ((((ks << 2) | hi) ^ bxor) << 3));
                sacc[ct] = __builtin_amdgcn_mfma_f32_16x16x32_bf16(a, b, sacc[ct], 0, 0, 0);
            }
        }
    }

    // ---- capture conv A1 (t1) fragments from Bs before it's overwritten ----
    // t1[row][f0+j] = Bs[(f0+j)*512 + ((row>>3)^j)*8 + (row&7)]   (f0 multiple of 8)
    s16x8 a1f[4];
    #pragma unroll
    for (int kk = 0; kk < 4; ++kk) {
        int f0 = kk * 32 + hi * 8;
        s16x8 t;
        #pragma unroll
        for (int j = 0; j < 8; ++j)
            t[j] = (short)Bs[(f0 + j) * 512 + (((row >> 3) ^ j) << 3) + (row & 7)];
        a1f[kk] = t;
    }
    __syncthreads();   // B reads + captures complete; reuse Bs[0..17408) as t2 tile [128][136]

    {
        int rloc = wave * 16 + (hi << 2);
        #pragma unroll
        for (int ct = 0; ct < 8; ++ct) {
            int col = ct * 16 + l15;
            #pragma unroll
            for (int r = 0; r < 4; ++r)
                Bs[(rloc + r) * 136 + col] = f2bf(sacc[ct][r]);
        }
    }
    __syncthreads();

    // ---- conv phase: h = A0@W0 + t1@W1 + t2@W2 ----
    f32x4 acc[8];
    #pragma unroll
    for (int ct = 0; ct < 8; ++ct) acc[ct] = (f32x4){0.f, 0.f, 0.f, 0.f};
    const int arow = id * 128 + lrow;
    #pragma unroll
    for (int ks = 0; ks < 12; ++ks) {
        s16x8 a;
        if (ks < 4) {
            a = *(const s16x8*)(A0 + (size_t)arow * F + ks * 32 + hi * 8);
        } else if (ks < 8) {
            a = a1f[ks - 4];
        } else {
            a = *(const s16x8*)(Bs + lrow * 136 + (ks - 8) * 32 + hi * 8);
        }
        const unsigned short* wb = Wswz + ((size_t)ks * 512 + lane) * 8;
        #pragma unroll
        for (int ct = 0; ct < 8; ++ct) {
            s16x8 b = *(const s16x8*)(wb + (size_t)ct * 512);
            acc[ct] = __builtin_amdgcn_mfma_f32_16x16x32_bf16(a, b, acc[ct], 0, 0, 0);
        }
    }

    const int rloc = wave * 16 + (hi << 2);
    if (WRITE_H) {
        unsigned short* OutS = Bs + 40960;   // disjoint from t2 tile [0,17408)
        #pragma unroll
        for (int ct = 0; ct < 8; ++ct) {
            int col = ct * 16 + l15;
            float b = bias[col];
            float v0 = fmaxf(acc[ct][0] + b, 0.f);
            float v1 = fmaxf(acc[ct][1] + b, 0.f);
            float v2 = fmaxf(acc[ct][2] + b, 0.f);
            float v3 = fmaxf(acc[ct][3] + b, 0.f);
            uint2 w;
            w.x = pack16(v0, v1);
            w.y = pack16(v2, v3);
            *(uint2*)(Hc + (size_t)g * F * NG + (size_t)col * NG + rt * 128 + rloc) = w;
            OutS[(rloc + 0) * F + col] = f2bf(v0);
            OutS[(rloc + 1) * F + col] = f2bf(v1);
            OutS[(rloc + 2) * F + col] = f2bf(v2);
            OutS[(rloc + 3) * F + col] = f2bf(v3);
        }
        __syncthreads();
        uint4* o4 = (uint4*)(Hr + ((size_t)g * NG + rt * 128) * F);
        const uint4* s4 = (const uint4*)OutS;
        #pragma unroll
        for (int u = tid; u < 128 * F / 8; u += 512) o4[u] = s4[u];
    } else {
        __syncthreads();   // t2-tile reads done before aliasing with wmax
        float* wmax = (float*)Bs;
        #pragma unroll
        for (int ct = 0; ct < 8; ++ct) {
            int col = ct * 16 + l15;
            float b = bias[col];
            float m = fmaxf(fmaxf(acc[ct][0], acc[ct][1]), fmaxf(acc[ct][2], acc[ct][3]));
            m = fmaxf(m + b, 0.f);
            m = fmaxf(m, __shfl_xor(m, 16));
            m = fmaxf(m, __shfl_xor(m, 32));
            if (lane < 16) wmax[wave * F + col] = m;
        }
        __syncthreads();
        if (tid < F) {
            float m = wmax[tid];
            #pragma unroll
            for (int w = 1; w < 8; ++w) m = fmaxf(m, wmax[w * F + tid]);
            pooledp[((size_t)rt * 64 + g) * F + tid] = m;
        }
    }
}

// ---------------- output head: pooled = max over 4 partials; out = pooled @ Wout + bout ----

__global__ __launch_bounds__(64) void out_gemm_kernel(const float* __restrict__ pooledp,
                                                      const float* __restrict__ Wout,
                                                      const float* __restrict__ bout,
                                                      float* __restrict__ out) {
    __shared__ float p[F];
    int b = blockIdx.x, t = threadIdx.x;
    #pragma unroll
    for (int c = t; c < F; c += 64) {
        float m = pooledp[(size_t)b * F + c];
        m = fmaxf(m, pooledp[((size_t)64 + b) * F + c]);
        m = fmaxf(m, pooledp[((size_t)128 + b) * F + c]);
        m = fmaxf(m, pooledp[((size_t)192 + b) * F + c]);
        p[c] = m;
    }
    __syncthreads();
    float acc = bout[t];
    #pragma unroll 8
    for (int k = 0; k < F; ++k) acc += p[k] * Wout[k * 64 + t];
    out[(size_t)b * 64 + t] = acc;
}

// ---------------- launch ----------------

extern "C" void kernel_launch(void* const* d_in, const int* in_sizes, int n_in,
                              void* d_out, int out_size, void* d_ws, size_t ws_size,
                              hipStream_t stream) {
    const float* X     = (const float*)d_in[0];
    const int*   ei    = (const int*)d_in[2];
    const float* W1    = (const float*)d_in[3];
    const float* b1    = (const float*)d_in[4];
    const float* W2    = (const float*)d_in[5];
    const float* b2    = (const float*)d_in[6];
    const float* Wout  = (const float*)d_in[7];
    const float* bout  = (const float*)d_in[8];
    const float* alpha = (const float*)d_in[9];

    const int N = in_sizes[0] / F;   // 32768
    const int E = in_sizes[2] / 2;   // 524288
    const int Bg = N / NG;           // 64

    const int* srcv = ei;
    const int* dstv = ei + E;

    char* ws = (char*)d_ws;
    const size_t CBYTES = (size_t)Bg * NG * NG / 2;   // 8.39 MB (u4 counts, lives all run)
    const size_t PBYTES = (size_t)N * F * 2;          // 8.39 MB

    unsigned int* cnt4 = (unsigned int*)ws;
    unsigned short* P0 = (unsigned short*)(ws + CBYTES);               // Xr -> h1r
    unsigned short* P1 = (unsigned short*)(ws + CBYTES + PBYTES);      // Xc -> h1c
    unsigned short* P3 = (unsigned short*)(ws + CBYTES + 2 * PBYTES);  // t1c / u1c
    char* tail = ws + CBYTES + 3 * PBYTES;
    unsigned short* Wswz1 = (unsigned short*)tail;
    unsigned short* Wswz2 = Wswz1 + (size_t)3 * F * F;
    float* pooledp = (float*)(Wswz2 + (size_t)3 * F * F);             // [4][64][128]

    // prep: cast X + shuffle weights + zero cnt (no in-graph memsets)
    prep_kernel<<<1408, 256, 0, stream>>>(X, P0, P1, W1, W2, Wswz1, Wswz2, (uint4*)cnt4);

    // edge-count scatter (nibbles)
    cnt_scatter_kernel<<<(E + 255) / 256, 256, 0, stream>>>(srcv, dstv, cnt4, E);

    // layer 1: t1c = S@X ; h1 = relu(X@W0 + t1@W1 + (S@t1)@W2 + b1)
    sapply_kernel<<<Bg * 4, 512, 0, stream>>>(cnt4, alpha, P1, P3);
    fused_conv_kernel<1><<<Bg * 4, 512, 0, stream>>>(cnt4, alpha, P3, P0, Wswz1, b1, P0, P1, nullptr);

    // layer 2: u1c = S@h1 ; pooledp = blockwise colmax(relu(h1@W0 + u1@W1 + (S@u1)@W2 + b2))
    sapply_kernel<<<Bg * 4, 512, 0, stream>>>(cnt4, alpha, P1, P3);
    fused_conv_kernel<0><<<Bg * 4, 512, 0, stream>>>(cnt4, alpha, P3, P0, Wswz2, b2, nullptr, nullptr, pooledp);

    // head
    out_gemm_kernel<<<Bg, 64, 0, stream>>>(pooledp, Wout, bout, (float*)d_out);
}